// Round 1
// 402.918 us; speedup vs baseline: 1.0160x; 1.0160x over previous
//
#include <hip/hip_runtime.h>
#include <hip/hip_fp16.h>
#include <math.h>

#define N_NODES 100000
#define N_EDGES 1600000
#define NEG_SLOPE 0.2f
#define EPS 1e-16f

__device__ __forceinline__ float lrelu(float v) { return v > 0.f ? v : NEG_SLOPE * v; }

// load 4 halfs -> float4 (single 8B load)
__device__ __forceinline__ float4 ld4h(const __half* p) {
    uint2 r = *(const uint2*)p;
    __half2 h0 = *reinterpret_cast<const __half2*>(&r.x);
    __half2 h1 = *reinterpret_cast<const __half2*>(&r.y);
    float2 f0 = __half22float2(h0), f1 = __half22float2(h1);
    return make_float4(f0.x, f0.y, f1.x, f1.y);
}

// ---------------------------------------------------------------- zero deg
__global__ void k_zero_deg(int* __restrict__ deg) {
    int i = blockIdx.x * blockDim.x + threadIdx.x;
    if (i < N_NODES) deg[i] = 0;
}

// ---------------------------------------------------------------- XCD-partitioned histogram of dst
#define HISTX_BLOCKS 2048
__global__ void k_hist_x(const int* __restrict__ ei, int* __restrict__ deg) {
    const int step = (N_NODES + 7) / 8;
    int xcd = blockIdx.x & 7;
    int lo = xcd * step;
    int hi = (lo + step < N_NODES) ? lo + step : N_NODES;
    int gid = (blockIdx.x >> 3) * blockDim.x + threadIdx.x;
    const int stride = (HISTX_BLOCKS >> 3) * 256;
    for (int e = gid; e < N_EDGES; e += stride) {
        int dst = ei[N_EDGES + e];
        if (dst >= lo && dst < hi) atomicAdd(&deg[dst], 1);
    }
}

// ---------------------------------------------------------------- scan level 1
__global__ void k_scan_part(const int* __restrict__ deg, int* __restrict__ loc,
                            int* __restrict__ partial) {
    __shared__ int tmp[256];
    int i = blockIdx.x * 256 + threadIdx.x;
    int v = (i < N_NODES) ? deg[i] : 0;
    tmp[threadIdx.x] = v;
    __syncthreads();
    for (int off = 1; off < 256; off <<= 1) {
        int t = (threadIdx.x >= off) ? tmp[threadIdx.x - off] : 0;
        __syncthreads();
        tmp[threadIdx.x] += t;
        __syncthreads();
    }
    if (i < N_NODES) loc[i] = tmp[threadIdx.x] - v;   // exclusive
    if (threadIdx.x == 255) partial[blockIdx.x] = tmp[255];
}

// ---------------------------------------------------------------- scan level 2 (nb <= 512)
__global__ void k_scan_tot(int* __restrict__ partial, int nb) {
    __shared__ int tmp[512];
    int v = (threadIdx.x < nb) ? partial[threadIdx.x] : 0;
    tmp[threadIdx.x] = v;
    __syncthreads();
    for (int off = 1; off < 512; off <<= 1) {
        int t = (threadIdx.x >= off) ? tmp[threadIdx.x - off] : 0;
        __syncthreads();
        tmp[threadIdx.x] += t;
        __syncthreads();
    }
    if (threadIdx.x < nb) partial[threadIdx.x] = tmp[threadIdx.x] - v;  // exclusive
}

// ---------------------------------------------------------------- scan level 3 + cursor init
__global__ void k_scan_add(const int* __restrict__ loc, const int* __restrict__ partial,
                           int* __restrict__ rowptr, int* __restrict__ cursor) {
    int i = blockIdx.x * blockDim.x + threadIdx.x;
    if (i < N_NODES) {
        int r = loc[i] + partial[i >> 8];
        rowptr[i] = r;
        cursor[i] = r;
    }
}

// ---------------------------------------------------------------- XCD-partitioned scatter
#define SCATX_BLOCKS 2048
__global__ void k_scatter_x(const int* __restrict__ ei, int* __restrict__ cursor,
                            int* __restrict__ csr_src) {
    const int step = (N_NODES + 7) / 8;
    int xcd = blockIdx.x & 7;
    int lo = xcd * step;
    int hi = (lo + step < N_NODES) ? lo + step : N_NODES;
    int gid = (blockIdx.x >> 3) * blockDim.x + threadIdx.x;
    const int stride = (SCATX_BLOCKS >> 3) * 256;
    for (int e = gid; e < N_EDGES; e += stride) {
        int dst = ei[N_EDGES + e];
        if (dst >= lo && dst < hi) {
            int pos = atomicAdd(&cursor[dst], 1);
            csr_src[pos] = ei[e];
        }
    }
}

// ---------------------------------------------------------------- K-Q: qs[h] = W1_h^T a_src_h, qd[h] = W1_h^T a_dst_h  (24 floats)
__global__ void k_q(const float* __restrict__ w1, const float* __restrict__ as1,
                    const float* __restrict__ ad1, float* __restrict__ qv) {
    int t = threadIdx.x;
    if (t >= 24) return;
    int c = t % 3, h = (t / 3) % 4, side = t / 12;
    const float* att = side ? ad1 : as1;
    float acc = 0.f;
    for (int cc = 0; cc < 32; cc++)
        acc += att[h * 32 + cc] * w1[(h * 32 + cc) * 3 + c];
    qv[t] = acc;
}

// ---------------------------------------------------------------- K-NODE1: a1d = x.qd ; p1[n] = {a1s[4], x0,x1,x2,1} (32B row)
__global__ void k_node1(const float* __restrict__ x, const float* __restrict__ qv,
                        float* __restrict__ a1d, float* __restrict__ p1) {
    int n = blockIdx.x * blockDim.x + threadIdx.x;
    if (n >= N_NODES) return;
    float x0 = x[n * 3], x1 = x[n * 3 + 1], x2 = x[n * 3 + 2];
    float4 s, d;
    s.x = x0 * qv[0]  + x1 * qv[1]  + x2 * qv[2];
    s.y = x0 * qv[3]  + x1 * qv[4]  + x2 * qv[5];
    s.z = x0 * qv[6]  + x1 * qv[7]  + x2 * qv[8];
    s.w = x0 * qv[9]  + x1 * qv[10] + x2 * qv[11];
    d.x = x0 * qv[12] + x1 * qv[13] + x2 * qv[14];
    d.y = x0 * qv[15] + x1 * qv[16] + x2 * qv[17];
    d.z = x0 * qv[18] + x1 * qv[19] + x2 * qv[20];
    d.w = x0 * qv[21] + x1 * qv[22] + x2 * qv[23];
    ((float4*)a1d)[n] = d;
    ((float4*)p1)[n * 2]     = s;
    float4 xx; xx.x = x0; xx.y = x1; xx.z = x2; xx.w = 1.f;
    ((float4*)p1)[n * 2 + 1] = xx;
}

// ---------------------------------------------------------------- K-GAT1: linearity trick, w2 in registers, packed p1 gathers
// Phase A v2: 4 lanes/node PARTITION the edge list (stride-4) and each lane
// computes all 4 heads in registers -> 2 gathers/edge instead of 8, no
// per-edge select chain. 16-value 4-lane shfl butterfly once per node.
#define G1_BLOCKS ((N_NODES + 63) / 64)
__global__ void k_gat1(const int* __restrict__ rowptr, const int* __restrict__ deg,
                       const int* __restrict__ csr_src,
                       const float* __restrict__ p1, const float* __restrict__ w1,
                       const float* __restrict__ a1d,
                       const float* __restrict__ b1, const float* __restrict__ w2,
                       const float* __restrict__ as2, const float* __restrict__ ad2,
                       float* __restrict__ h2, float* __restrict__ a2s, float* __restrict__ a2d) {
    __shared__ float sm[64][16];      // per-node: 4 heads x {s0,s1,s2,den}
    __shared__ float f1s[4][128];
    int tid = threadIdx.x;
    int wave = tid >> 6, lane = tid & 63;
    int o = lane & 31, half = lane >> 5;
    int k0 = half * 64;

    // ---- phase A: node = block*64 + wave*16 + (lane>>2); lane&3 = edge phase = head slot
    int nl = wave * 16 + (lane >> 2);
    int h  = lane & 3;
    int n  = blockIdx.x * 64 + nl;
    if (n < N_NODES) {
        float4 ad4 = ((const float4*)a1d)[n];          // broadcast across the quad
        float adv[4] = {ad4.x, ad4.y, ad4.z, ad4.w};
        int beg = rowptr[n], cnt = deg[n];
        float acc[4][4];                                // [head][{s0,s1,s2,den}]
        #pragma unroll
        for (int hh = 0; hh < 4; hh++)
            acc[hh][0] = acc[hh][1] = acc[hh][2] = acc[hh][3] = 0.f;
        int t = h;
        for (; t + 4 < cnt; t += 8) {                   // 2 edges/iter, 4 gathers in flight
            int i0 = csr_src[beg + t], i1 = csr_src[beg + t + 4];
            float4 A0 = ((const float4*)p1)[i0 * 2], X0 = ((const float4*)p1)[i0 * 2 + 1];
            float4 A1 = ((const float4*)p1)[i1 * 2], X1 = ((const float4*)p1)[i1 * 2 + 1];
            float a0v[4] = {A0.x, A0.y, A0.z, A0.w};
            float a1v[4] = {A1.x, A1.y, A1.z, A1.w};
            #pragma unroll
            for (int hh = 0; hh < 4; hh++) {
                float e0 = __expf(lrelu(a0v[hh] + adv[hh]));
                float e1 = __expf(lrelu(a1v[hh] + adv[hh]));
                acc[hh][0] += e0 * X0.x + e1 * X1.x;
                acc[hh][1] += e0 * X0.y + e1 * X1.y;
                acc[hh][2] += e0 * X0.z + e1 * X1.z;
                acc[hh][3] += e0 + e1;
            }
        }
        if (t < cnt) {                                  // at most 1 tail edge per lane
            int i0 = csr_src[beg + t];
            float4 A0 = ((const float4*)p1)[i0 * 2], X0 = ((const float4*)p1)[i0 * 2 + 1];
            float a0v[4] = {A0.x, A0.y, A0.z, A0.w};
            #pragma unroll
            for (int hh = 0; hh < 4; hh++) {
                float e0 = __expf(lrelu(a0v[hh] + adv[hh]));
                acc[hh][0] += e0 * X0.x;
                acc[hh][1] += e0 * X0.y;
                acc[hh][2] += e0 * X0.z;
                acc[hh][3] += e0;
            }
        }
        // 4-lane butterfly (quad is exec-uniform: same n) — every lane gets full sums
        #pragma unroll
        for (int hh = 0; hh < 4; hh++) {
            #pragma unroll
            for (int cc = 0; cc < 4; cc++) {
                float vv = acc[hh][cc];
                vv += __shfl_xor(vv, 1);
                vv += __shfl_xor(vv, 2);
                acc[hh][cc] = vv;
            }
        }
        float4 r;   // lane writes its own head's slice (static-index select, once per node)
        r.x = h == 0 ? acc[0][0] : h == 1 ? acc[1][0] : h == 2 ? acc[2][0] : acc[3][0];
        r.y = h == 0 ? acc[0][1] : h == 1 ? acc[1][1] : h == 2 ? acc[2][1] : acc[3][1];
        r.z = h == 0 ? acc[0][2] : h == 1 ? acc[1][2] : h == 2 ? acc[2][2] : acc[3][2];
        r.w = h == 0 ? acc[0][3] : h == 1 ? acc[1][3] : h == 2 ? acc[2][3] : acc[3][3];
        *(float4*)&sm[nl][h * 4] = r;
    }
    // same-wave LDS write->read below: no barrier needed

    // per-lane w2 column loaded AFTER phase A (keeps gather-loop VGPR pressure low)
    float w2r[64];
    {
        const float4* wp = (const float4*)(w2 + o * 128 + k0);
        #pragma unroll
        for (int q = 0; q < 16; q++) {
            float4 t = wp[q];
            w2r[q * 4 + 0] = t.x; w2r[q * 4 + 1] = t.y;
            w2r[q * 4 + 2] = t.z; w2r[q * 4 + 3] = t.w;
        }
    }

    // ---- phase B: wave processes its own 16 nodes
    int j = lane, j2 = lane + 64;
    int h0 = j >> 5;
    float wa0 = w1[j * 3], wa1 = w1[j * 3 + 1], wa2 = w1[j * 3 + 2];
    float wb0 = w1[j2 * 3], wb1 = w1[j2 * 3 + 1], wb2 = w1[j2 * 3 + 2];
    float b1j = b1[j], b1j2 = b1[j2];
    float as2o = as2[o], ad2o = ad2[o];
    const float* f = f1s[wave];

    #pragma unroll 1
    for (int i = 0; i < 16; i++) {
        int n2 = blockIdx.x * 64 + wave * 16 + i;
        if (n2 >= N_NODES) break;
        const float* S = sm[wave * 16 + i];
        float v0 = (wa0 * S[h0 * 4] + wa1 * S[h0 * 4 + 1] + wa2 * S[h0 * 4 + 2])
                   / (S[h0 * 4 + 3] + EPS) + b1j;
        float v1 = (wb0 * S[(2 + h0) * 4] + wb1 * S[(2 + h0) * 4 + 1] + wb2 * S[(2 + h0) * 4 + 2])
                   / (S[(2 + h0) * 4 + 3] + EPS) + b1j2;
        f1s[wave][j]  = v0 > 0.f ? v0 : expm1f(v0);
        f1s[wave][j2] = v1 > 0.f ? v1 : expm1f(v1);
        float acc = 0.f;
        #pragma unroll
        for (int t = 0; t < 64; t++)
            acc += f[k0 + t] * w2r[t];
        acc += __shfl_down(acc, 32);
        if (half == 0) {
            h2[n2 * 32 + o] = acc;
            float ps = acc * as2o, pd = acc * ad2o;
            #pragma unroll
            for (int off = 16; off; off >>= 1) {
                ps += __shfl_xor(ps, off);
                pd += __shfl_xor(pd, off);
            }
            if (o == 0) { a2s[n2] = ps; a2d[n2] = pd; }
        }
    }
}

// ---------------------------------------------------------------- K-GAT2: edge-broadcast via LDS staging (low LDS-pipe-op count)
// wave per node. Lane l owns edge (base+l): coalesced csr load, 1 gather +
// 1 expf per edge; (idx,e) staged in LDS as int2 -> 1 broadcast ds_read_b64
// per edge (replaces 2 bpermutes). Epilogue matvec: hf staged once, W rows
// read as 8x ds_read_b128 (pad 36 -> 16B-aligned, 4-way banks ~1.6x).
#define G2_BLOCKS 4096
__global__ void k_gat2(const int* __restrict__ rowptr, const int* __restrict__ deg,
                       const int* __restrict__ csr_src,
                       const float* __restrict__ h2, const float* __restrict__ a2s,
                       const float* __restrict__ a2d, const float* __restrict__ b2,
                       const float* __restrict__ mw1, const float* __restrict__ mb1,
                       __half* __restrict__ u, __half* __restrict__ v) {
    __shared__ float Ws2[2][32 * 36];    // [half][c*36+k]; row start 144B (16B-aligned)
    __shared__ int2  pk[4][64];          // per-wave staged (idx, e-bits)
    __shared__ float4 hfs[4][8];         // per-wave hf vector (32 floats)
    int tid = threadIdx.x;
    for (int i = tid; i < 2048; i += 256) {
        int c = i >> 6, col = i & 63;
        Ws2[col >> 5][c * 36 + (col & 31)] = mw1[i];
    }
    __syncthreads();
    int lane = tid & 63, w = tid >> 6;
    int c = lane & 31, half = lane >> 5;
    float bias = half ? 0.f : mb1[c];
    float b2c = b2[c];
    __half* outp = half ? v : u;
    const float4* Wr = (const float4*)&Ws2[half][c * 36];
    int wid = blockIdx.x * 4 + w;
    const int stride = G2_BLOCKS * 4;
    for (int n = wid; n < N_NODES; n += stride) {
        float ad = a2d[n];
        int beg = rowptr[n], cnt = deg[n];
        float acc = 0.f, den = 0.f;
        for (int base = 0; base < cnt; base += 64) {
            int li = base + lane;
            int idx = (li < cnt) ? csr_src[beg + li] : 0;   // coalesced
            float e = 0.f;
            if (li < cnt) e = __expf(lrelu(a2s[idx] + ad)); // 1 gather+expf per edge
            den += e;
            pk[w][lane] = make_int2(idx, __float_as_int(e)); // same-wave stage
            int m = cnt - base; if (m > 64) m = 64;
            int t = half;
            for (; t + 6 < m; t += 8) {      // 4 edges/half, 4 h2 loads in flight
                int2 p0 = pk[w][t],     p1 = pk[w][t + 2];
                int2 p2 = pk[w][t + 4], p3 = pk[w][t + 6];
                float g0 = h2[p0.x * 32 + c], g1 = h2[p1.x * 32 + c];
                float g2 = h2[p2.x * 32 + c], g3 = h2[p3.x * 32 + c];
                acc += __int_as_float(p0.y) * g0 + __int_as_float(p1.y) * g1
                     + __int_as_float(p2.y) * g2 + __int_as_float(p3.y) * g3;
            }
            for (; t + 2 < m; t += 4) {
                int2 p0 = pk[w][t], p1 = pk[w][t + 2];
                acc += __int_as_float(p0.y) * h2[p0.x * 32 + c]
                     + __int_as_float(p1.y) * h2[p1.x * 32 + c];
            }
            if (t < m) {
                int2 p0 = pk[w][t];
                acc += __int_as_float(p0.y) * h2[p0.x * 32 + c];
            }
        }
        acc += __shfl_xor(acc, 32);          // combine halves (channel c total)
        #pragma unroll
        for (int off = 32; off; off >>= 1) den += __shfl_xor(den, off);
        float hfc = acc / (den + EPS) + b2c;
        if (half == 0) ((float*)hfs[w])[c] = hfc;   // same-wave stage
        float r = bias;
        #pragma unroll
        for (int q = 0; q < 8; q++) {
            float4 Wq = Wr[q];               // 4-way bank (~1.6x), 8 ops
            float4 hq = hfs[w][q];           // wave-uniform broadcast, free
            r += Wq.x * hq.x + Wq.y * hq.y + Wq.z * hq.z + Wq.w * hq.w;
        }
        outp[n * 32 + c] = __float2half(r);
    }
}

// ---------------------------------------------------------------- K-MLP: 8 lanes/edge, 4 edges/iter, fp16 u/v rows (1 line each)
#define MLP_BLOCKS 4096
__global__ void k_mlp(const int* __restrict__ ei, const __half* __restrict__ u,
                      const __half* __restrict__ v, const float* __restrict__ mw2,
                      const float* __restrict__ mb2, float* __restrict__ out) {
    int tid = threadIdx.x;
    int q = tid & 7;
    float4 w2q = ((const float4*)mw2)[q];
    float mb20 = mb2[0];
    int g = blockIdx.x * 32 + (tid >> 3);
    const int stride = MLP_BLOCKS * 32 * 4;
    for (int e = g * 4; e < N_EDGES; e += stride) {
        int eb = e;
        int e1 = (eb + 1 < N_EDGES) ? eb + 1 : eb;
        int e2 = (eb + 2 < N_EDGES) ? eb + 2 : eb;
        int e3 = (eb + 3 < N_EDGES) ? eb + 3 : eb;
        int sa = ei[eb], da = ei[N_EDGES + eb];
        int sb = ei[e1], db = ei[N_EDGES + e1];
        int sc = ei[e2], dc = ei[N_EDGES + e2];
        int sd = ei[e3], dd = ei[N_EDGES + e3];
        float4 ua = ld4h(u + sa * 32 + q * 4);
        float4 va = ld4h(v + da * 32 + q * 4);
        float4 ub = ld4h(u + sb * 32 + q * 4);
        float4 vb = ld4h(v + db * 32 + q * 4);
        float4 uc = ld4h(u + sc * 32 + q * 4);
        float4 vc = ld4h(v + dc * 32 + q * 4);
        float4 ud = ld4h(u + sd * 32 + q * 4);
        float4 vd = ld4h(v + dd * 32 + q * 4);
        float s0 = fmaxf(ua.x + va.x, 0.f) * w2q.x + fmaxf(ua.y + va.y, 0.f) * w2q.y
                 + fmaxf(ua.z + va.z, 0.f) * w2q.z + fmaxf(ua.w + va.w, 0.f) * w2q.w;
        float s1 = fmaxf(ub.x + vb.x, 0.f) * w2q.x + fmaxf(ub.y + vb.y, 0.f) * w2q.y
                 + fmaxf(ub.z + vb.z, 0.f) * w2q.z + fmaxf(ub.w + vb.w, 0.f) * w2q.w;
        float s2 = fmaxf(uc.x + vc.x, 0.f) * w2q.x + fmaxf(uc.y + vc.y, 0.f) * w2q.y
                 + fmaxf(uc.z + vc.z, 0.f) * w2q.z + fmaxf(uc.w + vc.w, 0.f) * w2q.w;
        float s3 = fmaxf(ud.x + vd.x, 0.f) * w2q.x + fmaxf(ud.y + vd.y, 0.f) * w2q.y
                 + fmaxf(ud.z + vd.z, 0.f) * w2q.z + fmaxf(ud.w + vd.w, 0.f) * w2q.w;
        s0 += __shfl_xor(s0, 1, 8); s0 += __shfl_xor(s0, 2, 8); s0 += __shfl_xor(s0, 4, 8);
        s1 += __shfl_xor(s1, 1, 8); s1 += __shfl_xor(s1, 2, 8); s1 += __shfl_xor(s1, 4, 8);
        s2 += __shfl_xor(s2, 1, 8); s2 += __shfl_xor(s2, 2, 8); s2 += __shfl_xor(s2, 4, 8);
        s3 += __shfl_xor(s3, 1, 8); s3 += __shfl_xor(s3, 2, 8); s3 += __shfl_xor(s3, 4, 8);
        if (q == 0) {
            out[eb] = fmaxf(s0 + mb20, 0.f);
            if (eb + 1 < N_EDGES) out[eb + 1] = fmaxf(s1 + mb20, 0.f);
            if (eb + 2 < N_EDGES) out[eb + 2] = fmaxf(s2 + mb20, 0.f);
            if (eb + 3 < N_EDGES) out[eb + 3] = fmaxf(s3 + mb20, 0.f);
        }
    }
}

// ---------------------------------------------------------------- launch
extern "C" void kernel_launch(void* const* d_in, const int* in_sizes, int n_in,
                              void* d_out, int out_size, void* d_ws, size_t ws_size,
                              hipStream_t stream) {
    const float* x    = (const float*)d_in[0];
    const int*   ei   = (const int*)d_in[1];
    const float* w1   = (const float*)d_in[2];
    const float* as1  = (const float*)d_in[3];
    const float* ad1  = (const float*)d_in[4];
    const float* b1   = (const float*)d_in[5];
    const float* w2   = (const float*)d_in[6];
    const float* as2  = (const float*)d_in[7];
    const float* ad2  = (const float*)d_in[8];
    const float* b2   = (const float*)d_in[9];
    const float* mw1  = (const float*)d_in[10];
    const float* mb1  = (const float*)d_in[11];
    const float* mw2  = (const float*)d_in[12];
    const float* mb2  = (const float*)d_in[13];
    float* out = (float*)d_out;

    const int N = N_NODES;
    // byte-offset workspace layout; p1/h2/u/v 64B-aligned (offsets verified)
    char* base   = (char*)d_ws;
    int* deg     = (int*)(base);                      // N*4
    int* rowptr  = (int*)(base + 400000);             // N*4
    int* cursor  = (int*)(base + 800000);             // N*4
    int* loc     = (int*)(base + 1200000);            // N*4
    int* partial = (int*)(base + 1600000);            // 2048 B
    int* csr_src = (int*)(base + 1602048);            // E*4
    float* p1    = (float*)(base + 8002048);          // 8N*4   (%64==0)
    float* a1d   = (float*)(base + 11202048);         // 4N*4
    float* h2    = (float*)(base + 12802048);         // 32N*4  (%64==0)
    float* a2s   = (float*)(base + 25602048);         // N*4
    float* a2d   = (float*)(base + 26002048);         // N*4
    __half* u    = (__half*)(base + 26402048);        // 32N*2  (%64==0)
    __half* v    = (__half*)(base + 32802048);        // 32N*2  (%64==0)
    float* qv    = (float*)(base + 39202048);         // 24

    const int nb = (N + 255) / 256;

    k_zero_deg<<<nb, 256, 0, stream>>>(deg);
    k_hist_x<<<HISTX_BLOCKS, 256, 0, stream>>>(ei, deg);
    k_scan_part<<<nb, 256, 0, stream>>>(deg, loc, partial);
    k_scan_tot<<<1, 512, 0, stream>>>(partial, nb);
    k_scan_add<<<nb, 256, 0, stream>>>(loc, partial, rowptr, cursor);

    k_scatter_x<<<SCATX_BLOCKS, 256, 0, stream>>>(ei, cursor, csr_src);

    k_q<<<1, 32, 0, stream>>>(w1, as1, ad1, qv);
    k_node1<<<nb, 256, 0, stream>>>(x, qv, a1d, p1);

    k_gat1<<<G1_BLOCKS, 256, 0, stream>>>(rowptr, deg, csr_src, p1, w1, a1d,
                                          b1, w2, as2, ad2, h2, a2s, a2d);

    k_gat2<<<G2_BLOCKS, 256, 0, stream>>>(rowptr, deg, csr_src, h2, a2s, a2d, b2,
                                          mw1, mb1, u, v);

    k_mlp<<<MLP_BLOCKS, 256, 0, stream>>>(ei, u, v, mw2, mb2, out);
}

// Round 2
// 354.173 us; speedup vs baseline: 1.1558x; 1.1376x over previous
//
#include <hip/hip_runtime.h>
#include <hip/hip_fp16.h>
#include <math.h>

#define N_NODES 100000
#define N_EDGES 1600000
#define NEG_SLOPE 0.2f
#define EPS 1e-16f

__device__ __forceinline__ float lrelu(float v) { return v > 0.f ? v : NEG_SLOPE * v; }

// load 4 halfs -> float4 (single 8B load)
__device__ __forceinline__ float4 ld4h(const __half* p) {
    uint2 r = *(const uint2*)p;
    __half2 h0 = *reinterpret_cast<const __half2*>(&r.x);
    __half2 h1 = *reinterpret_cast<const __half2*>(&r.y);
    float2 f0 = __half22float2(h0), f1 = __half22float2(h1);
    return make_float4(f0.x, f0.y, f1.x, f1.y);
}

// ---------------------------------------------------------------- zero deg
__global__ void k_zero_deg(int* __restrict__ deg) {
    int i = blockIdx.x * blockDim.x + threadIdx.x;
    if (i < N_NODES) deg[i] = 0;
}

// ---------------------------------------------------------------- single-pass hist + rank record
// p = old count of dst; pack (src | rank<<17): src < 2^17, rank << 2^15 for E/N=16.
#define HIST_BLOCKS 2048
__global__ void k_hist(const int* __restrict__ ei, int* __restrict__ deg,
                       int* __restrict__ packed) {
    int gid = blockIdx.x * 256 + threadIdx.x;
    const int stride = HIST_BLOCKS * 256;
    for (int e = gid; e < N_EDGES; e += stride) {
        int src = ei[e];
        int dst = ei[N_EDGES + e];
        int p = atomicAdd(&deg[dst], 1);
        packed[e] = src | (p << 17);
    }
}

// ---------------------------------------------------------------- scan level 1
__global__ void k_scan_part(const int* __restrict__ deg, int* __restrict__ loc,
                            int* __restrict__ partial) {
    __shared__ int tmp[256];
    int i = blockIdx.x * 256 + threadIdx.x;
    int v = (i < N_NODES) ? deg[i] : 0;
    tmp[threadIdx.x] = v;
    __syncthreads();
    for (int off = 1; off < 256; off <<= 1) {
        int t = (threadIdx.x >= off) ? tmp[threadIdx.x - off] : 0;
        __syncthreads();
        tmp[threadIdx.x] += t;
        __syncthreads();
    }
    if (i < N_NODES) loc[i] = tmp[threadIdx.x] - v;   // exclusive
    if (threadIdx.x == 255) partial[blockIdx.x] = tmp[255];
}

// ---------------------------------------------------------------- scan level 2 (nb <= 512)
__global__ void k_scan_tot(int* __restrict__ partial, int nb) {
    __shared__ int tmp[512];
    int v = (threadIdx.x < nb) ? partial[threadIdx.x] : 0;
    tmp[threadIdx.x] = v;
    __syncthreads();
    for (int off = 1; off < 512; off <<= 1) {
        int t = (threadIdx.x >= off) ? tmp[threadIdx.x - off] : 0;
        __syncthreads();
        tmp[threadIdx.x] += t;
        __syncthreads();
    }
    if (threadIdx.x < nb) partial[threadIdx.x] = tmp[threadIdx.x] - v;  // exclusive
}

// ---------------------------------------------------------------- scan level 3 (rowptr only; no cursor)
__global__ void k_scan_add(const int* __restrict__ loc, const int* __restrict__ partial,
                           int* __restrict__ rowptr) {
    int i = blockIdx.x * blockDim.x + threadIdx.x;
    if (i < N_NODES) rowptr[i] = loc[i] + partial[i >> 8];
}

// ---------------------------------------------------------------- atomic-free scatter via recorded ranks
#define SCAT_BLOCKS 2048
__global__ void k_scatter(const int* __restrict__ ei, const int* __restrict__ packed,
                          const int* __restrict__ rowptr, int* __restrict__ csr_src) {
    int gid = blockIdx.x * 256 + threadIdx.x;
    const int stride = SCAT_BLOCKS * 256;
    for (int e = gid; e < N_EDGES; e += stride) {
        int dst = ei[N_EDGES + e];
        int pk = packed[e];
        csr_src[rowptr[dst] + (pk >> 17)] = pk & 0x1FFFF;
    }
}

// ---------------------------------------------------------------- K-Q: qs[h] = W1_h^T a_src_h, qd[h] = W1_h^T a_dst_h  (24 floats)
__global__ void k_q(const float* __restrict__ w1, const float* __restrict__ as1,
                    const float* __restrict__ ad1, float* __restrict__ qv) {
    int t = threadIdx.x;
    if (t >= 24) return;
    int c = t % 3, h = (t / 3) % 4, side = t / 12;
    const float* att = side ? ad1 : as1;
    float acc = 0.f;
    for (int cc = 0; cc < 32; cc++)
        acc += att[h * 32 + cc] * w1[(h * 32 + cc) * 3 + c];
    qv[t] = acc;
}

// ---------------------------------------------------------------- K-NODE1: a1d = x.qd ; p1[n] = {a1s[4], x0,x1,x2,1} (32B row)
__global__ void k_node1(const float* __restrict__ x, const float* __restrict__ qv,
                        float* __restrict__ a1d, float* __restrict__ p1) {
    int n = blockIdx.x * blockDim.x + threadIdx.x;
    if (n >= N_NODES) return;
    float x0 = x[n * 3], x1 = x[n * 3 + 1], x2 = x[n * 3 + 2];
    float4 s, d;
    s.x = x0 * qv[0]  + x1 * qv[1]  + x2 * qv[2];
    s.y = x0 * qv[3]  + x1 * qv[4]  + x2 * qv[5];
    s.z = x0 * qv[6]  + x1 * qv[7]  + x2 * qv[8];
    s.w = x0 * qv[9]  + x1 * qv[10] + x2 * qv[11];
    d.x = x0 * qv[12] + x1 * qv[13] + x2 * qv[14];
    d.y = x0 * qv[15] + x1 * qv[16] + x2 * qv[17];
    d.z = x0 * qv[18] + x1 * qv[19] + x2 * qv[20];
    d.w = x0 * qv[21] + x1 * qv[22] + x2 * qv[23];
    ((float4*)a1d)[n] = d;
    ((float4*)p1)[n * 2]     = s;
    float4 xx; xx.x = x0; xx.y = x1; xx.z = x2; xx.w = 1.f;
    ((float4*)p1)[n * 2 + 1] = xx;
}

// ---------------------------------------------------------------- K-GAT1: linearity trick, w2 in registers, packed p1 gathers
// Phase A v2: 4 lanes/node PARTITION the edge list (stride-4) and each lane
// computes all 4 heads in registers -> 2 gathers/edge instead of 8, no
// per-edge select chain. 16-value 4-lane shfl butterfly once per node.
#define G1_BLOCKS ((N_NODES + 63) / 64)
__global__ void k_gat1(const int* __restrict__ rowptr, const int* __restrict__ deg,
                       const int* __restrict__ csr_src,
                       const float* __restrict__ p1, const float* __restrict__ w1,
                       const float* __restrict__ a1d,
                       const float* __restrict__ b1, const float* __restrict__ w2,
                       const float* __restrict__ as2, const float* __restrict__ ad2,
                       float* __restrict__ h2, float* __restrict__ a2s, float* __restrict__ a2d) {
    __shared__ float sm[64][16];      // per-node: 4 heads x {s0,s1,s2,den}
    __shared__ float f1s[4][128];
    int tid = threadIdx.x;
    int wave = tid >> 6, lane = tid & 63;
    int o = lane & 31, half = lane >> 5;
    int k0 = half * 64;

    // ---- phase A: node = block*64 + wave*16 + (lane>>2); lane&3 = edge phase = head slot
    int nl = wave * 16 + (lane >> 2);
    int h  = lane & 3;
    int n  = blockIdx.x * 64 + nl;
    if (n < N_NODES) {
        float4 ad4 = ((const float4*)a1d)[n];          // broadcast across the quad
        float adv[4] = {ad4.x, ad4.y, ad4.z, ad4.w};
        int beg = rowptr[n], cnt = deg[n];
        float acc[4][4];                                // [head][{s0,s1,s2,den}]
        #pragma unroll
        for (int hh = 0; hh < 4; hh++)
            acc[hh][0] = acc[hh][1] = acc[hh][2] = acc[hh][3] = 0.f;
        int t = h;
        for (; t + 4 < cnt; t += 8) {                   // 2 edges/iter, 4 gathers in flight
            int i0 = csr_src[beg + t], i1 = csr_src[beg + t + 4];
            float4 A0 = ((const float4*)p1)[i0 * 2], X0 = ((const float4*)p1)[i0 * 2 + 1];
            float4 A1 = ((const float4*)p1)[i1 * 2], X1 = ((const float4*)p1)[i1 * 2 + 1];
            float a0v[4] = {A0.x, A0.y, A0.z, A0.w};
            float a1v[4] = {A1.x, A1.y, A1.z, A1.w};
            #pragma unroll
            for (int hh = 0; hh < 4; hh++) {
                float e0 = __expf(lrelu(a0v[hh] + adv[hh]));
                float e1 = __expf(lrelu(a1v[hh] + adv[hh]));
                acc[hh][0] += e0 * X0.x + e1 * X1.x;
                acc[hh][1] += e0 * X0.y + e1 * X1.y;
                acc[hh][2] += e0 * X0.z + e1 * X1.z;
                acc[hh][3] += e0 + e1;
            }
        }
        if (t < cnt) {                                  // at most 1 tail edge per lane
            int i0 = csr_src[beg + t];
            float4 A0 = ((const float4*)p1)[i0 * 2], X0 = ((const float4*)p1)[i0 * 2 + 1];
            float a0v[4] = {A0.x, A0.y, A0.z, A0.w};
            #pragma unroll
            for (int hh = 0; hh < 4; hh++) {
                float e0 = __expf(lrelu(a0v[hh] + adv[hh]));
                acc[hh][0] += e0 * X0.x;
                acc[hh][1] += e0 * X0.y;
                acc[hh][2] += e0 * X0.z;
                acc[hh][3] += e0;
            }
        }
        // 4-lane butterfly (quad is exec-uniform: same n) — every lane gets full sums
        #pragma unroll
        for (int hh = 0; hh < 4; hh++) {
            #pragma unroll
            for (int cc = 0; cc < 4; cc++) {
                float vv = acc[hh][cc];
                vv += __shfl_xor(vv, 1);
                vv += __shfl_xor(vv, 2);
                acc[hh][cc] = vv;
            }
        }
        float4 r;   // lane writes its own head's slice (static-index select, once per node)
        r.x = h == 0 ? acc[0][0] : h == 1 ? acc[1][0] : h == 2 ? acc[2][0] : acc[3][0];
        r.y = h == 0 ? acc[0][1] : h == 1 ? acc[1][1] : h == 2 ? acc[2][1] : acc[3][1];
        r.z = h == 0 ? acc[0][2] : h == 1 ? acc[1][2] : h == 2 ? acc[2][2] : acc[3][2];
        r.w = h == 0 ? acc[0][3] : h == 1 ? acc[1][3] : h == 2 ? acc[2][3] : acc[3][3];
        *(float4*)&sm[nl][h * 4] = r;
    }
    // same-wave LDS write->read below: no barrier needed

    // per-lane w2 column loaded AFTER phase A (keeps gather-loop VGPR pressure low)
    float w2r[64];
    {
        const float4* wp = (const float4*)(w2 + o * 128 + k0);
        #pragma unroll
        for (int q = 0; q < 16; q++) {
            float4 t = wp[q];
            w2r[q * 4 + 0] = t.x; w2r[q * 4 + 1] = t.y;
            w2r[q * 4 + 2] = t.z; w2r[q * 4 + 3] = t.w;
        }
    }

    // ---- phase B: wave processes its own 16 nodes
    int j = lane, j2 = lane + 64;
    int h0 = j >> 5;
    float wa0 = w1[j * 3], wa1 = w1[j * 3 + 1], wa2 = w1[j * 3 + 2];
    float wb0 = w1[j2 * 3], wb1 = w1[j2 * 3 + 1], wb2 = w1[j2 * 3 + 2];
    float b1j = b1[j], b1j2 = b1[j2];
    float as2o = as2[o], ad2o = ad2[o];
    const float* f = f1s[wave];

    #pragma unroll 1
    for (int i = 0; i < 16; i++) {
        int n2 = blockIdx.x * 64 + wave * 16 + i;
        if (n2 >= N_NODES) break;
        const float* S = sm[wave * 16 + i];
        float v0 = (wa0 * S[h0 * 4] + wa1 * S[h0 * 4 + 1] + wa2 * S[h0 * 4 + 2])
                   / (S[h0 * 4 + 3] + EPS) + b1j;
        float v1 = (wb0 * S[(2 + h0) * 4] + wb1 * S[(2 + h0) * 4 + 1] + wb2 * S[(2 + h0) * 4 + 2])
                   / (S[(2 + h0) * 4 + 3] + EPS) + b1j2;
        f1s[wave][j]  = v0 > 0.f ? v0 : expm1f(v0);
        f1s[wave][j2] = v1 > 0.f ? v1 : expm1f(v1);
        float acc = 0.f;
        #pragma unroll
        for (int t = 0; t < 64; t++)
            acc += f[k0 + t] * w2r[t];
        acc += __shfl_down(acc, 32);
        if (half == 0) {
            h2[n2 * 32 + o] = acc;
            float ps = acc * as2o, pd = acc * ad2o;
            #pragma unroll
            for (int off = 16; off; off >>= 1) {
                ps += __shfl_xor(ps, off);
                pd += __shfl_xor(pd, off);
            }
            if (o == 0) { a2s[n2] = ps; a2d[n2] = pd; }
        }
    }
}

// ---------------------------------------------------------------- K-GAT2: edge-broadcast via LDS staging (low LDS-pipe-op count)
// wave per node. Lane l owns edge (base+l): coalesced csr load, 1 gather +
// 1 expf per edge; (idx,e) staged in LDS as int2 -> 1 broadcast ds_read_b64
// per edge (replaces 2 bpermutes). Epilogue matvec: hf staged once, W rows
// read as 8x ds_read_b128 (pad 36 -> 16B-aligned, 4-way banks ~1.6x).
#define G2_BLOCKS 4096
__global__ void k_gat2(const int* __restrict__ rowptr, const int* __restrict__ deg,
                       const int* __restrict__ csr_src,
                       const float* __restrict__ h2, const float* __restrict__ a2s,
                       const float* __restrict__ a2d, const float* __restrict__ b2,
                       const float* __restrict__ mw1, const float* __restrict__ mb1,
                       __half* __restrict__ u, __half* __restrict__ v) {
    __shared__ float Ws2[2][32 * 36];    // [half][c*36+k]; row start 144B (16B-aligned)
    __shared__ int2  pk[4][64];          // per-wave staged (idx, e-bits)
    __shared__ float4 hfs[4][8];         // per-wave hf vector (32 floats)
    int tid = threadIdx.x;
    for (int i = tid; i < 2048; i += 256) {
        int c = i >> 6, col = i & 63;
        Ws2[col >> 5][c * 36 + (col & 31)] = mw1[i];
    }
    __syncthreads();
    int lane = tid & 63, w = tid >> 6;
    int c = lane & 31, half = lane >> 5;
    float bias = half ? 0.f : mb1[c];
    float b2c = b2[c];
    __half* outp = half ? v : u;
    const float4* Wr = (const float4*)&Ws2[half][c * 36];
    int wid = blockIdx.x * 4 + w;
    const int stride = G2_BLOCKS * 4;
    for (int n = wid; n < N_NODES; n += stride) {
        float ad = a2d[n];
        int beg = rowptr[n], cnt = deg[n];
        float acc = 0.f, den = 0.f;
        for (int base = 0; base < cnt; base += 64) {
            int li = base + lane;
            int idx = (li < cnt) ? csr_src[beg + li] : 0;   // coalesced
            float e = 0.f;
            if (li < cnt) e = __expf(lrelu(a2s[idx] + ad)); // 1 gather+expf per edge
            den += e;
            pk[w][lane] = make_int2(idx, __float_as_int(e)); // same-wave stage
            int m = cnt - base; if (m > 64) m = 64;
            int t = half;
            for (; t + 6 < m; t += 8) {      // 4 edges/half, 4 h2 loads in flight
                int2 p0 = pk[w][t],     p1 = pk[w][t + 2];
                int2 p2 = pk[w][t + 4], p3 = pk[w][t + 6];
                float g0 = h2[p0.x * 32 + c], g1 = h2[p1.x * 32 + c];
                float g2 = h2[p2.x * 32 + c], g3 = h2[p3.x * 32 + c];
                acc += __int_as_float(p0.y) * g0 + __int_as_float(p1.y) * g1
                     + __int_as_float(p2.y) * g2 + __int_as_float(p3.y) * g3;
            }
            for (; t + 2 < m; t += 4) {
                int2 p0 = pk[w][t], p1 = pk[w][t + 2];
                acc += __int_as_float(p0.y) * h2[p0.x * 32 + c]
                     + __int_as_float(p1.y) * h2[p1.x * 32 + c];
            }
            if (t < m) {
                int2 p0 = pk[w][t];
                acc += __int_as_float(p0.y) * h2[p0.x * 32 + c];
            }
        }
        acc += __shfl_xor(acc, 32);          // combine halves (channel c total)
        #pragma unroll
        for (int off = 32; off; off >>= 1) den += __shfl_xor(den, off);
        float hfc = acc / (den + EPS) + b2c;
        if (half == 0) ((float*)hfs[w])[c] = hfc;   // same-wave stage
        float r = bias;
        #pragma unroll
        for (int q = 0; q < 8; q++) {
            float4 Wq = Wr[q];               // 4-way bank (~1.6x), 8 ops
            float4 hq = hfs[w][q];           // wave-uniform broadcast, free
            r += Wq.x * hq.x + Wq.y * hq.y + Wq.z * hq.z + Wq.w * hq.w;
        }
        outp[n * 32 + c] = __float2half(r);
    }
}

// ---------------------------------------------------------------- K-MLP: 8 lanes/edge, 4 edges/iter, fp16 u/v rows (1 line each)
#define MLP_BLOCKS 4096
__global__ void k_mlp(const int* __restrict__ ei, const __half* __restrict__ u,
                      const __half* __restrict__ v, const float* __restrict__ mw2,
                      const float* __restrict__ mb2, float* __restrict__ out) {
    int tid = threadIdx.x;
    int q = tid & 7;
    float4 w2q = ((const float4*)mw2)[q];
    float mb20 = mb2[0];
    int g = blockIdx.x * 32 + (tid >> 3);
    const int stride = MLP_BLOCKS * 32 * 4;
    for (int e = g * 4; e < N_EDGES; e += stride) {
        int eb = e;
        int e1 = (eb + 1 < N_EDGES) ? eb + 1 : eb;
        int e2 = (eb + 2 < N_EDGES) ? eb + 2 : eb;
        int e3 = (eb + 3 < N_EDGES) ? eb + 3 : eb;
        int sa = ei[eb], da = ei[N_EDGES + eb];
        int sb = ei[e1], db = ei[N_EDGES + e1];
        int sc = ei[e2], dc = ei[N_EDGES + e2];
        int sd = ei[e3], dd = ei[N_EDGES + e3];
        float4 ua = ld4h(u + sa * 32 + q * 4);
        float4 va = ld4h(v + da * 32 + q * 4);
        float4 ub = ld4h(u + sb * 32 + q * 4);
        float4 vb = ld4h(v + db * 32 + q * 4);
        float4 uc = ld4h(u + sc * 32 + q * 4);
        float4 vc = ld4h(v + dc * 32 + q * 4);
        float4 ud = ld4h(u + sd * 32 + q * 4);
        float4 vd = ld4h(v + dd * 32 + q * 4);
        float s0 = fmaxf(ua.x + va.x, 0.f) * w2q.x + fmaxf(ua.y + va.y, 0.f) * w2q.y
                 + fmaxf(ua.z + va.z, 0.f) * w2q.z + fmaxf(ua.w + va.w, 0.f) * w2q.w;
        float s1 = fmaxf(ub.x + vb.x, 0.f) * w2q.x + fmaxf(ub.y + vb.y, 0.f) * w2q.y
                 + fmaxf(ub.z + vb.z, 0.f) * w2q.z + fmaxf(ub.w + vb.w, 0.f) * w2q.w;
        float s2 = fmaxf(uc.x + vc.x, 0.f) * w2q.x + fmaxf(uc.y + vc.y, 0.f) * w2q.y
                 + fmaxf(uc.z + vc.z, 0.f) * w2q.z + fmaxf(uc.w + vc.w, 0.f) * w2q.w;
        float s3 = fmaxf(ud.x + vd.x, 0.f) * w2q.x + fmaxf(ud.y + vd.y, 0.f) * w2q.y
                 + fmaxf(ud.z + vd.z, 0.f) * w2q.z + fmaxf(ud.w + vd.w, 0.f) * w2q.w;
        s0 += __shfl_xor(s0, 1, 8); s0 += __shfl_xor(s0, 2, 8); s0 += __shfl_xor(s0, 4, 8);
        s1 += __shfl_xor(s1, 1, 8); s1 += __shfl_xor(s1, 2, 8); s1 += __shfl_xor(s1, 4, 8);
        s2 += __shfl_xor(s2, 1, 8); s2 += __shfl_xor(s2, 2, 8); s2 += __shfl_xor(s2, 4, 8);
        s3 += __shfl_xor(s3, 1, 8); s3 += __shfl_xor(s3, 2, 8); s3 += __shfl_xor(s3, 4, 8);
        if (q == 0) {
            out[eb] = fmaxf(s0 + mb20, 0.f);
            if (eb + 1 < N_EDGES) out[eb + 1] = fmaxf(s1 + mb20, 0.f);
            if (eb + 2 < N_EDGES) out[eb + 2] = fmaxf(s2 + mb20, 0.f);
            if (eb + 3 < N_EDGES) out[eb + 3] = fmaxf(s3 + mb20, 0.f);
        }
    }
}

// ---------------------------------------------------------------- launch
extern "C" void kernel_launch(void* const* d_in, const int* in_sizes, int n_in,
                              void* d_out, int out_size, void* d_ws, size_t ws_size,
                              hipStream_t stream) {
    const float* x    = (const float*)d_in[0];
    const int*   ei   = (const int*)d_in[1];
    const float* w1   = (const float*)d_in[2];
    const float* as1  = (const float*)d_in[3];
    const float* ad1  = (const float*)d_in[4];
    const float* b1   = (const float*)d_in[5];
    const float* w2   = (const float*)d_in[6];
    const float* as2  = (const float*)d_in[7];
    const float* ad2  = (const float*)d_in[8];
    const float* b2   = (const float*)d_in[9];
    const float* mw1  = (const float*)d_in[10];
    const float* mb1  = (const float*)d_in[11];
    const float* mw2  = (const float*)d_in[12];
    const float* mb2  = (const float*)d_in[13];
    float* out = (float*)d_out;

    const int N = N_NODES;
    // byte-offset workspace layout; p1/h2/u/v 64B-aligned (offsets verified)
    char* base   = (char*)d_ws;
    int* deg     = (int*)(base);                      // N*4
    int* rowptr  = (int*)(base + 400000);             // N*4
    int* loc     = (int*)(base + 1200000);            // N*4
    int* partial = (int*)(base + 1600000);            // 2048 B
    int* csr_src = (int*)(base + 1602048);            // E*4
    float* p1    = (float*)(base + 8002048);          // 8N*4   (%64==0)
    float* a1d   = (float*)(base + 11202048);         // 4N*4
    float* h2    = (float*)(base + 12802048);         // 32N*4  (%64==0)
    int* packed  = (int*)(base + 12802048);           // E*4, aliases h2 (disjoint lifetime:
                                                      // packed dead before k_gat1 writes h2)
    float* a2s   = (float*)(base + 25602048);         // N*4
    float* a2d   = (float*)(base + 26002048);         // N*4
    __half* u    = (__half*)(base + 26402048);        // 32N*2  (%64==0)
    __half* v    = (__half*)(base + 32802048);        // 32N*2  (%64==0)
    float* qv    = (float*)(base + 39202048);         // 24

    const int nb = (N + 255) / 256;

    k_zero_deg<<<nb, 256, 0, stream>>>(deg);
    k_hist<<<HIST_BLOCKS, 256, 0, stream>>>(ei, deg, packed);
    k_scan_part<<<nb, 256, 0, stream>>>(deg, loc, partial);
    k_scan_tot<<<1, 512, 0, stream>>>(partial, nb);
    k_scan_add<<<nb, 256, 0, stream>>>(loc, partial, rowptr);

    k_scatter<<<SCAT_BLOCKS, 256, 0, stream>>>(ei, packed, rowptr, csr_src);

    k_q<<<1, 32, 0, stream>>>(w1, as1, ad1, qv);
    k_node1<<<nb, 256, 0, stream>>>(x, qv, a1d, p1);

    k_gat1<<<G1_BLOCKS, 256, 0, stream>>>(rowptr, deg, csr_src, p1, w1, a1d,
                                          b1, w2, as2, ad2, h2, a2s, a2d);

    k_gat2<<<G2_BLOCKS, 256, 0, stream>>>(rowptr, deg, csr_src, h2, a2s, a2d, b2,
                                          mw1, mb1, u, v);

    k_mlp<<<MLP_BLOCKS, 256, 0, stream>>>(ei, u, v, mw2, mb2, out);
}

// Round 3
// 308.172 us; speedup vs baseline: 1.3283x; 1.1493x over previous
//
#include <hip/hip_runtime.h>
#include <hip/hip_fp16.h>
#include <math.h>

#define N_NODES 100000
#define N_EDGES 1600000
#define NEG_SLOPE 0.2f
#define EPS 1e-16f

// bucket sort geometry: 196 buckets of 512 nodes; 391 blocks x 4096 edges
#define NBUCK 196
#define CHUNK 4096
#define BLKB 391

__device__ __forceinline__ float lrelu(float v) { return v > 0.f ? v : NEG_SLOPE * v; }

// load 4 halfs -> float4 (single 8B load)
__device__ __forceinline__ float4 ld4h(const __half* p) {
    uint2 r = *(const uint2*)p;
    __half2 h0 = *reinterpret_cast<const __half2*>(&r.x);
    __half2 h1 = *reinterpret_cast<const __half2*>(&r.y);
    float2 f0 = __half22float2(h0), f1 = __half22float2(h1);
    return make_float4(f0.x, f0.y, f1.x, f1.y);
}

// ---------------------------------------------------------------- Pass A: per-block coarse histogram (LDS only)
__global__ void kA_hist(const int* __restrict__ ei, int* __restrict__ bh) {
    __shared__ int hist[NBUCK];
    int tid = threadIdx.x, b = blockIdx.x;
    if (tid < NBUCK) hist[tid] = 0;
    __syncthreads();
    int base = b * CHUNK;
    #pragma unroll
    for (int i = 0; i < CHUNK / 256; i++) {
        int e = base + i * 256 + tid;
        if (e < N_EDGES) {
            int dst = ei[N_EDGES + e];
            atomicAdd(&hist[dst >> 9], 1);
        }
    }
    __syncthreads();
    if (tid < NBUCK) bh[b * NBUCK + tid] = hist[tid];
}

// ---------------------------------------------------------------- S1: column scan of bh (one block per bucket)
__global__ void kS1(int* __restrict__ bh, int* __restrict__ bucketStart) {
    __shared__ int tsum[256];
    int k = blockIdx.x, t = threadIdx.x;
    int j0 = 2 * t, j1 = 2 * t + 1;
    int v0 = (j0 < BLKB) ? bh[j0 * NBUCK + k] : 0;
    int v1 = (j1 < BLKB) ? bh[j1 * NBUCK + k] : 0;
    int s = v0 + v1;
    tsum[t] = s;
    __syncthreads();
    for (int off = 1; off < 256; off <<= 1) {
        int tv = (t >= off) ? tsum[t - off] : 0;
        __syncthreads();
        tsum[t] += tv;
        __syncthreads();
    }
    int excl = tsum[t] - s;
    if (j0 < BLKB) bh[j0 * NBUCK + k] = excl;
    if (j1 < BLKB) bh[j1 * NBUCK + k] = excl + v0;
    if (t == 255) bucketStart[k] = tsum[255];   // column total (scanned by S2)
}

// ---------------------------------------------------------------- S2: scan bucket totals -> bucket starts (+ total at [NBUCK])
__global__ void kS2(int* __restrict__ bucketStart) {
    __shared__ int tmp[256];
    int t = threadIdx.x;
    int v = (t < NBUCK) ? bucketStart[t] : 0;
    tmp[t] = v;
    __syncthreads();
    for (int off = 1; off < 256; off <<= 1) {
        int tv = (t >= off) ? tmp[t - off] : 0;
        __syncthreads();
        tmp[t] += tv;
        __syncthreads();
    }
    if (t < NBUCK) bucketStart[t] = tmp[t] - v;
    if (t == NBUCK - 1) bucketStart[NBUCK] = tmp[t];
}

// ---------------------------------------------------------------- Pass B: bin edges by coarse bucket (LDS cursors, coalesced-run writes)
__global__ void kB_bin(const int* __restrict__ ei, const int* __restrict__ bh,
                       const int* __restrict__ bucketStart, int* __restrict__ binned) {
    __shared__ int cur[NBUCK];
    int tid = threadIdx.x, b = blockIdx.x;
    if (tid < NBUCK) cur[tid] = bucketStart[tid] + bh[b * NBUCK + tid];
    __syncthreads();
    int base = b * CHUNK;
    #pragma unroll
    for (int i = 0; i < CHUNK / 256; i++) {
        int e = base + i * 256 + tid;
        if (e < N_EDGES) {
            int src = ei[e], dst = ei[N_EDGES + e];
            int pos = atomicAdd(&cur[dst >> 9], 1);
            binned[pos] = src | ((dst & 511) << 17);
        }
    }
}

// ---------------------------------------------------------------- Pass C: per-bucket counting sort -> deg, rowptr, csr_src
__global__ void kC_sort(const int* __restrict__ bucketStart, const int* __restrict__ binned,
                        int* __restrict__ deg, int* __restrict__ rowptr,
                        int* __restrict__ csr_src) {
    __shared__ int cnt[512];
    __shared__ int pfx[512];
    __shared__ int bsum[256];
    int t = threadIdx.x, k = blockIdx.x;
    int s0 = bucketStart[k], s1 = bucketStart[k + 1];
    cnt[t] = 0; cnt[t + 256] = 0;
    __syncthreads();
    for (int i = s0 + t; i < s1; i += 256)
        atomicAdd(&cnt[binned[i] >> 17], 1);
    __syncthreads();
    int a0 = cnt[2 * t], a1 = cnt[2 * t + 1];
    int s = a0 + a1;
    bsum[t] = s;
    __syncthreads();
    for (int off = 1; off < 256; off <<= 1) {
        int tv = (t >= off) ? bsum[t - off] : 0;
        __syncthreads();
        bsum[t] += tv;
        __syncthreads();
    }
    int excl = bsum[t] - s;
    pfx[2 * t] = excl;
    pfx[2 * t + 1] = excl + a0;
    int nb0 = k << 9;
    int n0 = nb0 + 2 * t, n1 = nb0 + 2 * t + 1;
    if (n0 < N_NODES) { deg[n0] = a0; rowptr[n0] = s0 + excl; }
    if (n1 < N_NODES) { deg[n1] = a1; rowptr[n1] = s0 + excl + a0; }
    __syncthreads();
    for (int i = s0 + t; i < s1; i += 256) {
        int pkd = binned[i];
        int pos = s0 + atomicAdd(&pfx[pkd >> 17], 1);
        csr_src[pos] = pkd & 0x1FFFF;
    }
}

// ---------------------------------------------------------------- K-Q: qs[h] = W1_h^T a_src_h, qd[h] = W1_h^T a_dst_h  (24 floats)
__global__ void k_q(const float* __restrict__ w1, const float* __restrict__ as1,
                    const float* __restrict__ ad1, float* __restrict__ qv) {
    int t = threadIdx.x;
    if (t >= 24) return;
    int c = t % 3, h = (t / 3) % 4, side = t / 12;
    const float* att = side ? ad1 : as1;
    float acc = 0.f;
    for (int cc = 0; cc < 32; cc++)
        acc += att[h * 32 + cc] * w1[(h * 32 + cc) * 3 + c];
    qv[t] = acc;
}

// ---------------------------------------------------------------- K-NODE1: a1d = x.qd ; p1[n] = {a1s[4], x0,x1,x2,1} (32B row)
__global__ void k_node1(const float* __restrict__ x, const float* __restrict__ qv,
                        float* __restrict__ a1d, float* __restrict__ p1) {
    int n = blockIdx.x * blockDim.x + threadIdx.x;
    if (n >= N_NODES) return;
    float x0 = x[n * 3], x1 = x[n * 3 + 1], x2 = x[n * 3 + 2];
    float4 s, d;
    s.x = x0 * qv[0]  + x1 * qv[1]  + x2 * qv[2];
    s.y = x0 * qv[3]  + x1 * qv[4]  + x2 * qv[5];
    s.z = x0 * qv[6]  + x1 * qv[7]  + x2 * qv[8];
    s.w = x0 * qv[9]  + x1 * qv[10] + x2 * qv[11];
    d.x = x0 * qv[12] + x1 * qv[13] + x2 * qv[14];
    d.y = x0 * qv[15] + x1 * qv[16] + x2 * qv[17];
    d.z = x0 * qv[18] + x1 * qv[19] + x2 * qv[20];
    d.w = x0 * qv[21] + x1 * qv[22] + x2 * qv[23];
    ((float4*)a1d)[n] = d;
    ((float4*)p1)[n * 2]     = s;
    float4 xx; xx.x = x0; xx.y = x1; xx.z = x2; xx.w = 1.f;
    ((float4*)p1)[n * 2 + 1] = xx;
}

// ---------------------------------------------------------------- K-GAT1: linearity trick, w2 in registers, packed p1 gathers
// Phase A v2: 4 lanes/node PARTITION the edge list (stride-4) and each lane
// computes all 4 heads in registers -> 2 gathers/edge instead of 8, no
// per-edge select chain. 16-value 4-lane shfl butterfly once per node.
#define G1_BLOCKS ((N_NODES + 63) / 64)
__global__ void k_gat1(const int* __restrict__ rowptr, const int* __restrict__ deg,
                       const int* __restrict__ csr_src,
                       const float* __restrict__ p1, const float* __restrict__ w1,
                       const float* __restrict__ a1d,
                       const float* __restrict__ b1, const float* __restrict__ w2,
                       const float* __restrict__ as2, const float* __restrict__ ad2,
                       float* __restrict__ h2, float* __restrict__ a2s, float* __restrict__ a2d) {
    __shared__ float sm[64][16];      // per-node: 4 heads x {s0,s1,s2,den}
    __shared__ float f1s[4][128];
    int tid = threadIdx.x;
    int wave = tid >> 6, lane = tid & 63;
    int o = lane & 31, half = lane >> 5;
    int k0 = half * 64;

    // ---- phase A: node = block*64 + wave*16 + (lane>>2); lane&3 = edge phase = head slot
    int nl = wave * 16 + (lane >> 2);
    int h  = lane & 3;
    int n  = blockIdx.x * 64 + nl;
    if (n < N_NODES) {
        float4 ad4 = ((const float4*)a1d)[n];          // broadcast across the quad
        float adv[4] = {ad4.x, ad4.y, ad4.z, ad4.w};
        int beg = rowptr[n], cnt = deg[n];
        float acc[4][4];                                // [head][{s0,s1,s2,den}]
        #pragma unroll
        for (int hh = 0; hh < 4; hh++)
            acc[hh][0] = acc[hh][1] = acc[hh][2] = acc[hh][3] = 0.f;
        int t = h;
        for (; t + 4 < cnt; t += 8) {                   // 2 edges/iter, 4 gathers in flight
            int i0 = csr_src[beg + t], i1 = csr_src[beg + t + 4];
            float4 A0 = ((const float4*)p1)[i0 * 2], X0 = ((const float4*)p1)[i0 * 2 + 1];
            float4 A1 = ((const float4*)p1)[i1 * 2], X1 = ((const float4*)p1)[i1 * 2 + 1];
            float a0v[4] = {A0.x, A0.y, A0.z, A0.w};
            float a1v[4] = {A1.x, A1.y, A1.z, A1.w};
            #pragma unroll
            for (int hh = 0; hh < 4; hh++) {
                float e0 = __expf(lrelu(a0v[hh] + adv[hh]));
                float e1 = __expf(lrelu(a1v[hh] + adv[hh]));
                acc[hh][0] += e0 * X0.x + e1 * X1.x;
                acc[hh][1] += e0 * X0.y + e1 * X1.y;
                acc[hh][2] += e0 * X0.z + e1 * X1.z;
                acc[hh][3] += e0 + e1;
            }
        }
        if (t < cnt) {                                  // at most 1 tail edge per lane
            int i0 = csr_src[beg + t];
            float4 A0 = ((const float4*)p1)[i0 * 2], X0 = ((const float4*)p1)[i0 * 2 + 1];
            float a0v[4] = {A0.x, A0.y, A0.z, A0.w};
            #pragma unroll
            for (int hh = 0; hh < 4; hh++) {
                float e0 = __expf(lrelu(a0v[hh] + adv[hh]));
                acc[hh][0] += e0 * X0.x;
                acc[hh][1] += e0 * X0.y;
                acc[hh][2] += e0 * X0.z;
                acc[hh][3] += e0;
            }
        }
        // 4-lane butterfly (quad is exec-uniform: same n) — every lane gets full sums
        #pragma unroll
        for (int hh = 0; hh < 4; hh++) {
            #pragma unroll
            for (int cc = 0; cc < 4; cc++) {
                float vv = acc[hh][cc];
                vv += __shfl_xor(vv, 1);
                vv += __shfl_xor(vv, 2);
                acc[hh][cc] = vv;
            }
        }
        float4 r;   // lane writes its own head's slice (static-index select, once per node)
        r.x = h == 0 ? acc[0][0] : h == 1 ? acc[1][0] : h == 2 ? acc[2][0] : acc[3][0];
        r.y = h == 0 ? acc[0][1] : h == 1 ? acc[1][1] : h == 2 ? acc[2][1] : acc[3][1];
        r.z = h == 0 ? acc[0][2] : h == 1 ? acc[1][2] : h == 2 ? acc[2][2] : acc[3][2];
        r.w = h == 0 ? acc[0][3] : h == 1 ? acc[1][3] : h == 2 ? acc[2][3] : acc[3][3];
        *(float4*)&sm[nl][h * 4] = r;
    }
    // same-wave LDS write->read below: no barrier needed

    // per-lane w2 column loaded AFTER phase A (keeps gather-loop VGPR pressure low)
    float w2r[64];
    {
        const float4* wp = (const float4*)(w2 + o * 128 + k0);
        #pragma unroll
        for (int q = 0; q < 16; q++) {
            float4 t = wp[q];
            w2r[q * 4 + 0] = t.x; w2r[q * 4 + 1] = t.y;
            w2r[q * 4 + 2] = t.z; w2r[q * 4 + 3] = t.w;
        }
    }

    // ---- phase B: wave processes its own 16 nodes
    int j = lane, j2 = lane + 64;
    int h0 = j >> 5;
    float wa0 = w1[j * 3], wa1 = w1[j * 3 + 1], wa2 = w1[j * 3 + 2];
    float wb0 = w1[j2 * 3], wb1 = w1[j2 * 3 + 1], wb2 = w1[j2 * 3 + 2];
    float b1j = b1[j], b1j2 = b1[j2];
    float as2o = as2[o], ad2o = ad2[o];
    const float* f = f1s[wave];

    #pragma unroll 1
    for (int i = 0; i < 16; i++) {
        int n2 = blockIdx.x * 64 + wave * 16 + i;
        if (n2 >= N_NODES) break;
        const float* S = sm[wave * 16 + i];
        float v0 = (wa0 * S[h0 * 4] + wa1 * S[h0 * 4 + 1] + wa2 * S[h0 * 4 + 2])
                   / (S[h0 * 4 + 3] + EPS) + b1j;
        float v1 = (wb0 * S[(2 + h0) * 4] + wb1 * S[(2 + h0) * 4 + 1] + wb2 * S[(2 + h0) * 4 + 2])
                   / (S[(2 + h0) * 4 + 3] + EPS) + b1j2;
        f1s[wave][j]  = v0 > 0.f ? v0 : expm1f(v0);
        f1s[wave][j2] = v1 > 0.f ? v1 : expm1f(v1);
        float acc = 0.f;
        #pragma unroll
        for (int t = 0; t < 64; t++)
            acc += f[k0 + t] * w2r[t];
        acc += __shfl_down(acc, 32);
        if (half == 0) {
            h2[n2 * 32 + o] = acc;
            float ps = acc * as2o, pd = acc * ad2o;
            #pragma unroll
            for (int off = 16; off; off >>= 1) {
                ps += __shfl_xor(ps, off);
                pd += __shfl_xor(pd, off);
            }
            if (o == 0) { a2s[n2] = ps; a2d[n2] = pd; }
        }
    }
}

// ---------------------------------------------------------------- K-GAT2 v2: float4 h2 gathers (8 VMEM/edge instead of 32)
// wave per node. Lane = (edge-subgroup eg = lane>>3, channel-quad qq = lane&7).
// exp phase: lane owns edge base+lane (1 gather+expf), stages (idx,e) in LDS.
// aggregation: 8 edges/pass, each lane reads pk broadcast + one dwordx4 of h2.
// Node end: 3-step shfl butterfly (8/16/32) reduces edge-subgroups; lanes 0..7
// hold channel-quad sums -> hfs. Epilogue matvec unchanged.
#define G2_BLOCKS 4096
__global__ void k_gat2(const int* __restrict__ rowptr, const int* __restrict__ deg,
                       const int* __restrict__ csr_src,
                       const float* __restrict__ h2, const float* __restrict__ a2s,
                       const float* __restrict__ a2d, const float* __restrict__ b2,
                       const float* __restrict__ mw1, const float* __restrict__ mb1,
                       __half* __restrict__ u, __half* __restrict__ v) {
    __shared__ float Ws2[2][32 * 36];    // [half][c*36+k]; row start 144B (16B-aligned)
    __shared__ int2  pk[4][64];          // per-wave staged (idx, e-bits)
    __shared__ float4 hfs[4][8];         // per-wave hf vector (32 floats)
    int tid = threadIdx.x;
    for (int i = tid; i < 2048; i += 256) {
        int c = i >> 6, col = i & 63;
        Ws2[col >> 5][c * 36 + (col & 31)] = mw1[i];
    }
    __syncthreads();
    int lane = tid & 63, w = tid >> 6;
    int qq = lane & 7, eg = lane >> 3;
    int c = lane & 31, half = lane >> 5;
    float4 b2q = ((const float4*)b2)[qq];
    float bias = half ? 0.f : mb1[c];
    __half* outp = half ? v : u;
    const float4* Wr = (const float4*)&Ws2[half][c * 36];
    int wid = blockIdx.x * 4 + w;
    const int stride = G2_BLOCKS * 4;
    for (int n = wid; n < N_NODES; n += stride) {
        float ad = a2d[n];
        int beg = rowptr[n], cnt = deg[n];
        float4 acc4 = make_float4(0.f, 0.f, 0.f, 0.f);
        float den = 0.f;
        for (int base = 0; base < cnt; base += 64) {
            int li = base + lane;
            int idx = (li < cnt) ? csr_src[beg + li] : 0;   // coalesced
            float e = 0.f;
            if (li < cnt) e = __expf(lrelu(a2s[idx] + ad)); // 1 gather+expf per edge
            den += e;
            pk[w][lane] = make_int2(idx, __float_as_int(e)); // same-wave stage (e=0 pads)
            #pragma unroll
            for (int p = 0; p < 8; p++) {
                int2 pe = pk[w][p * 8 + eg];                 // ds_read_b64 broadcast x8 lanes
                float4 g = ((const float4*)(h2 + pe.x * 32))[qq];  // dwordx4 gather
                float ee = __int_as_float(pe.y);             // 0 for pad edges
                acc4.x += ee * g.x; acc4.y += ee * g.y;
                acc4.z += ee * g.z; acc4.w += ee * g.w;
            }
        }
        // reduce across edge-subgroups: lanes with same qq, eg in {0..7}
        #pragma unroll
        for (int off = 8; off < 64; off <<= 1) {
            acc4.x += __shfl_xor(acc4.x, off);
            acc4.y += __shfl_xor(acc4.y, off);
            acc4.z += __shfl_xor(acc4.z, off);
            acc4.w += __shfl_xor(acc4.w, off);
        }
        #pragma unroll
        for (int off = 32; off; off >>= 1) den += __shfl_xor(den, off);
        float inv = 1.f / (den + EPS);
        float4 hfc;
        hfc.x = acc4.x * inv + b2q.x;
        hfc.y = acc4.y * inv + b2q.y;
        hfc.z = acc4.z * inv + b2q.z;
        hfc.w = acc4.w * inv + b2q.w;
        if (lane < 8) hfs[w][lane] = hfc;    // lane<8 => eg=0, qq=lane; same-wave stage
        float r = bias;
        #pragma unroll
        for (int q = 0; q < 8; q++) {
            float4 Wq = Wr[q];               // 4-way bank (~1.6x), 8 ops
            float4 hq = hfs[w][q];           // wave-uniform broadcast, free
            r += Wq.x * hq.x + Wq.y * hq.y + Wq.z * hq.z + Wq.w * hq.w;
        }
        outp[n * 32 + c] = __float2half(r);
    }
}

// ---------------------------------------------------------------- K-MLP: 8 lanes/edge, 4 edges/iter, fp16 u/v rows (1 line each)
#define MLP_BLOCKS 4096
__global__ void k_mlp(const int* __restrict__ ei, const __half* __restrict__ u,
                      const __half* __restrict__ v, const float* __restrict__ mw2,
                      const float* __restrict__ mb2, float* __restrict__ out) {
    int tid = threadIdx.x;
    int q = tid & 7;
    float4 w2q = ((const float4*)mw2)[q];
    float mb20 = mb2[0];
    int g = blockIdx.x * 32 + (tid >> 3);
    const int stride = MLP_BLOCKS * 32 * 4;
    for (int e = g * 4; e < N_EDGES; e += stride) {
        int eb = e;
        int e1 = (eb + 1 < N_EDGES) ? eb + 1 : eb;
        int e2 = (eb + 2 < N_EDGES) ? eb + 2 : eb;
        int e3 = (eb + 3 < N_EDGES) ? eb + 3 : eb;
        int sa = ei[eb], da = ei[N_EDGES + eb];
        int sb = ei[e1], db = ei[N_EDGES + e1];
        int sc = ei[e2], dc = ei[N_EDGES + e2];
        int sd = ei[e3], dd = ei[N_EDGES + e3];
        float4 ua = ld4h(u + sa * 32 + q * 4);
        float4 va = ld4h(v + da * 32 + q * 4);
        float4 ub = ld4h(u + sb * 32 + q * 4);
        float4 vb = ld4h(v + db * 32 + q * 4);
        float4 uc = ld4h(u + sc * 32 + q * 4);
        float4 vc = ld4h(v + dc * 32 + q * 4);
        float4 ud = ld4h(u + sd * 32 + q * 4);
        float4 vd = ld4h(v + dd * 32 + q * 4);
        float s0 = fmaxf(ua.x + va.x, 0.f) * w2q.x + fmaxf(ua.y + va.y, 0.f) * w2q.y
                 + fmaxf(ua.z + va.z, 0.f) * w2q.z + fmaxf(ua.w + va.w, 0.f) * w2q.w;
        float s1 = fmaxf(ub.x + vb.x, 0.f) * w2q.x + fmaxf(ub.y + vb.y, 0.f) * w2q.y
                 + fmaxf(ub.z + vb.z, 0.f) * w2q.z + fmaxf(ub.w + vb.w, 0.f) * w2q.w;
        float s2 = fmaxf(uc.x + vc.x, 0.f) * w2q.x + fmaxf(uc.y + vc.y, 0.f) * w2q.y
                 + fmaxf(uc.z + vc.z, 0.f) * w2q.z + fmaxf(uc.w + vc.w, 0.f) * w2q.w;
        float s3 = fmaxf(ud.x + vd.x, 0.f) * w2q.x + fmaxf(ud.y + vd.y, 0.f) * w2q.y
                 + fmaxf(ud.z + vd.z, 0.f) * w2q.z + fmaxf(ud.w + vd.w, 0.f) * w2q.w;
        s0 += __shfl_xor(s0, 1, 8); s0 += __shfl_xor(s0, 2, 8); s0 += __shfl_xor(s0, 4, 8);
        s1 += __shfl_xor(s1, 1, 8); s1 += __shfl_xor(s1, 2, 8); s1 += __shfl_xor(s1, 4, 8);
        s2 += __shfl_xor(s2, 1, 8); s2 += __shfl_xor(s2, 2, 8); s2 += __shfl_xor(s2, 4, 8);
        s3 += __shfl_xor(s3, 1, 8); s3 += __shfl_xor(s3, 2, 8); s3 += __shfl_xor(s3, 4, 8);
        if (q == 0) {
            out[eb] = fmaxf(s0 + mb20, 0.f);
            if (eb + 1 < N_EDGES) out[eb + 1] = fmaxf(s1 + mb20, 0.f);
            if (eb + 2 < N_EDGES) out[eb + 2] = fmaxf(s2 + mb20, 0.f);
            if (eb + 3 < N_EDGES) out[eb + 3] = fmaxf(s3 + mb20, 0.f);
        }
    }
}

// ---------------------------------------------------------------- launch
extern "C" void kernel_launch(void* const* d_in, const int* in_sizes, int n_in,
                              void* d_out, int out_size, void* d_ws, size_t ws_size,
                              hipStream_t stream) {
    const float* x    = (const float*)d_in[0];
    const int*   ei   = (const int*)d_in[1];
    const float* w1   = (const float*)d_in[2];
    const float* as1  = (const float*)d_in[3];
    const float* ad1  = (const float*)d_in[4];
    const float* b1   = (const float*)d_in[5];
    const float* w2   = (const float*)d_in[6];
    const float* as2  = (const float*)d_in[7];
    const float* ad2  = (const float*)d_in[8];
    const float* b2   = (const float*)d_in[9];
    const float* mw1  = (const float*)d_in[10];
    const float* mb1  = (const float*)d_in[11];
    const float* mw2  = (const float*)d_in[12];
    const float* mb2  = (const float*)d_in[13];
    float* out = (float*)d_out;

    const int N = N_NODES;
    // byte-offset workspace layout; p1/h2/u/v 64B-aligned (offsets verified)
    char* base   = (char*)d_ws;
    int* deg     = (int*)(base);                      // N*4
    int* rowptr  = (int*)(base + 400000);             // N*4
    int* bstart  = (int*)(base + 800000);             // (NBUCK+1)*4 = 788 B
    int* bh      = (int*)(base + 1200000);            // BLKB*NBUCK*4 = 306,544 B
    int* csr_src = (int*)(base + 1602048);            // E*4
    float* p1    = (float*)(base + 8002048);          // 8N*4   (%64==0)
    float* a1d   = (float*)(base + 11202048);         // 4N*4
    float* h2    = (float*)(base + 12802048);         // 32N*4  (%64==0)
    int* binned  = (int*)(base + 12802048);           // E*4, aliases h2 (disjoint lifetime:
                                                      // binned dead before k_gat1 writes h2)
    float* a2s   = (float*)(base + 25602048);         // N*4
    float* a2d   = (float*)(base + 26002048);         // N*4
    __half* u    = (__half*)(base + 26402048);        // 32N*2  (%64==0)
    __half* v    = (__half*)(base + 32802048);        // 32N*2  (%64==0)
    float* qv    = (float*)(base + 39202048);         // 24

    const int nb = (N + 255) / 256;

    kA_hist<<<BLKB, 256, 0, stream>>>(ei, bh);
    kS1<<<NBUCK, 256, 0, stream>>>(bh, bstart);
    kS2<<<1, 256, 0, stream>>>(bstart);
    kB_bin<<<BLKB, 256, 0, stream>>>(ei, bh, bstart, binned);
    kC_sort<<<NBUCK, 256, 0, stream>>>(bstart, binned, deg, rowptr, csr_src);

    k_q<<<1, 32, 0, stream>>>(w1, as1, ad1, qv);
    k_node1<<<nb, 256, 0, stream>>>(x, qv, a1d, p1);

    k_gat1<<<G1_BLOCKS, 256, 0, stream>>>(rowptr, deg, csr_src, p1, w1, a1d,
                                          b1, w2, as2, ad2, h2, a2s, a2d);

    k_gat2<<<G2_BLOCKS, 256, 0, stream>>>(rowptr, deg, csr_src, h2, a2s, a2d, b2,
                                          mw1, mb1, u, v);

    k_mlp<<<MLP_BLOCKS, 256, 0, stream>>>(ei, u, v, mw2, mb2, out);
}

// Round 4
// 308.026 us; speedup vs baseline: 1.3290x; 1.0005x over previous
//
#include <hip/hip_runtime.h>
#include <hip/hip_fp16.h>
#include <math.h>

#define N_NODES 100000
#define N_EDGES 1600000
#define NEG_SLOPE 0.2f
#define EPS 1e-16f

// bucket sort geometry: 196 buckets of 512 nodes; 391 blocks x 4096 edges
#define NBUCK 196
#define CHUNK 4096
#define BLKB 391

__device__ __forceinline__ float lrelu(float v) { return v > 0.f ? v : NEG_SLOPE * v; }

// load 4 halfs -> float4 (single 8B load)
__device__ __forceinline__ float4 ld4h(const __half* p) {
    uint2 r = *(const uint2*)p;
    __half2 h0 = *reinterpret_cast<const __half2*>(&r.x);
    __half2 h1 = *reinterpret_cast<const __half2*>(&r.y);
    float2 f0 = __half22float2(h0), f1 = __half22float2(h1);
    return make_float4(f0.x, f0.y, f1.x, f1.y);
}

// ---------------------------------------------------------------- Pass A: per-block coarse histogram (LDS only)
__global__ void kA_hist(const int* __restrict__ ei, int* __restrict__ bh) {
    __shared__ int hist[NBUCK];
    int tid = threadIdx.x, b = blockIdx.x;
    if (tid < NBUCK) hist[tid] = 0;
    __syncthreads();
    int base = b * CHUNK;
    #pragma unroll
    for (int i = 0; i < CHUNK / 256; i++) {
        int e = base + i * 256 + tid;
        if (e < N_EDGES) {
            int dst = ei[N_EDGES + e];
            atomicAdd(&hist[dst >> 9], 1);
        }
    }
    __syncthreads();
    if (tid < NBUCK) bh[b * NBUCK + tid] = hist[tid];
}

// ---------------------------------------------------------------- S1: column scan of bh (one block per bucket)
__global__ void kS1(int* __restrict__ bh, int* __restrict__ bucketStart) {
    __shared__ int tsum[256];
    int k = blockIdx.x, t = threadIdx.x;
    int j0 = 2 * t, j1 = 2 * t + 1;
    int v0 = (j0 < BLKB) ? bh[j0 * NBUCK + k] : 0;
    int v1 = (j1 < BLKB) ? bh[j1 * NBUCK + k] : 0;
    int s = v0 + v1;
    tsum[t] = s;
    __syncthreads();
    for (int off = 1; off < 256; off <<= 1) {
        int tv = (t >= off) ? tsum[t - off] : 0;
        __syncthreads();
        tsum[t] += tv;
        __syncthreads();
    }
    int excl = tsum[t] - s;
    if (j0 < BLKB) bh[j0 * NBUCK + k] = excl;
    if (j1 < BLKB) bh[j1 * NBUCK + k] = excl + v0;
    if (t == 255) bucketStart[k] = tsum[255];   // column total (scanned by S2)
}

// ---------------------------------------------------------------- S2: scan bucket totals -> bucket starts (+ total at [NBUCK])
__global__ void kS2(int* __restrict__ bucketStart) {
    __shared__ int tmp[256];
    int t = threadIdx.x;
    int v = (t < NBUCK) ? bucketStart[t] : 0;
    tmp[t] = v;
    __syncthreads();
    for (int off = 1; off < 256; off <<= 1) {
        int tv = (t >= off) ? tmp[t - off] : 0;
        __syncthreads();
        tmp[t] += tv;
        __syncthreads();
    }
    if (t < NBUCK) bucketStart[t] = tmp[t] - v;
    if (t == NBUCK - 1) bucketStart[NBUCK] = tmp[t];
}

// ---------------------------------------------------------------- Pass B: bin edges by coarse bucket (LDS cursors, coalesced-run writes)
__global__ void kB_bin(const int* __restrict__ ei, const int* __restrict__ bh,
                       const int* __restrict__ bucketStart, int* __restrict__ binned) {
    __shared__ int cur[NBUCK];
    int tid = threadIdx.x, b = blockIdx.x;
    if (tid < NBUCK) cur[tid] = bucketStart[tid] + bh[b * NBUCK + tid];
    __syncthreads();
    int base = b * CHUNK;
    #pragma unroll
    for (int i = 0; i < CHUNK / 256; i++) {
        int e = base + i * 256 + tid;
        if (e < N_EDGES) {
            int src = ei[e], dst = ei[N_EDGES + e];
            int pos = atomicAdd(&cur[dst >> 9], 1);
            binned[pos] = src | ((dst & 511) << 17);
        }
    }
}

// ---------------------------------------------------------------- Pass C: per-bucket counting sort -> deg, rowptr, csr_src
__global__ void kC_sort(const int* __restrict__ bucketStart, const int* __restrict__ binned,
                        int* __restrict__ deg, int* __restrict__ rowptr,
                        int* __restrict__ csr_src) {
    __shared__ int cnt[512];
    __shared__ int pfx[512];
    __shared__ int bsum[256];
    int t = threadIdx.x, k = blockIdx.x;
    int s0 = bucketStart[k], s1 = bucketStart[k + 1];
    cnt[t] = 0; cnt[t + 256] = 0;
    __syncthreads();
    for (int i = s0 + t; i < s1; i += 256)
        atomicAdd(&cnt[binned[i] >> 17], 1);
    __syncthreads();
    int a0 = cnt[2 * t], a1 = cnt[2 * t + 1];
    int s = a0 + a1;
    bsum[t] = s;
    __syncthreads();
    for (int off = 1; off < 256; off <<= 1) {
        int tv = (t >= off) ? bsum[t - off] : 0;
        __syncthreads();
        bsum[t] += tv;
        __syncthreads();
    }
    int excl = bsum[t] - s;
    pfx[2 * t] = excl;
    pfx[2 * t + 1] = excl + a0;
    int nb0 = k << 9;
    int n0 = nb0 + 2 * t, n1 = nb0 + 2 * t + 1;
    if (n0 < N_NODES) { deg[n0] = a0; rowptr[n0] = s0 + excl; }
    if (n1 < N_NODES) { deg[n1] = a1; rowptr[n1] = s0 + excl + a0; }
    __syncthreads();
    for (int i = s0 + t; i < s1; i += 256) {
        int pkd = binned[i];
        int pos = s0 + atomicAdd(&pfx[pkd >> 17], 1);
        csr_src[pos] = pkd & 0x1FFFF;
    }
}

// ---------------------------------------------------------------- K-Q: qs[h] = W1_h^T a_src_h, qd[h] = W1_h^T a_dst_h  (24 floats)
__global__ void k_q(const float* __restrict__ w1, const float* __restrict__ as1,
                    const float* __restrict__ ad1, float* __restrict__ qv) {
    int t = threadIdx.x;
    if (t >= 24) return;
    int c = t % 3, h = (t / 3) % 4, side = t / 12;
    const float* att = side ? ad1 : as1;
    float acc = 0.f;
    for (int cc = 0; cc < 32; cc++)
        acc += att[h * 32 + cc] * w1[(h * 32 + cc) * 3 + c];
    qv[t] = acc;
}

// ---------------------------------------------------------------- K-NODE1: a1d = x.qd ; p1[n] = {a1s[4], x0,x1,x2,1} (32B row)
__global__ void k_node1(const float* __restrict__ x, const float* __restrict__ qv,
                        float* __restrict__ a1d, float* __restrict__ p1) {
    int n = blockIdx.x * blockDim.x + threadIdx.x;
    if (n >= N_NODES) return;
    float x0 = x[n * 3], x1 = x[n * 3 + 1], x2 = x[n * 3 + 2];
    float4 s, d;
    s.x = x0 * qv[0]  + x1 * qv[1]  + x2 * qv[2];
    s.y = x0 * qv[3]  + x1 * qv[4]  + x2 * qv[5];
    s.z = x0 * qv[6]  + x1 * qv[7]  + x2 * qv[8];
    s.w = x0 * qv[9]  + x1 * qv[10] + x2 * qv[11];
    d.x = x0 * qv[12] + x1 * qv[13] + x2 * qv[14];
    d.y = x0 * qv[15] + x1 * qv[16] + x2 * qv[17];
    d.z = x0 * qv[18] + x1 * qv[19] + x2 * qv[20];
    d.w = x0 * qv[21] + x1 * qv[22] + x2 * qv[23];
    ((float4*)a1d)[n] = d;
    ((float4*)p1)[n * 2]     = s;
    float4 xx; xx.x = x0; xx.y = x1; xx.z = x2; xx.w = 1.f;
    ((float4*)p1)[n * 2 + 1] = xx;
}

// ---------------------------------------------------------------- K-GAT1: linearity trick, w2 in registers, packed p1 gathers
// Phase A v2: 4 lanes/node PARTITION the edge list (stride-4) and each lane
// computes all 4 heads in registers -> 2 gathers/edge instead of 8, no
// per-edge select chain. 16-value 4-lane shfl butterfly once per node.
// h2 now stored fp16 (64-B rows) to halve k_gat2's L2-miss footprint.
#define G1_BLOCKS ((N_NODES + 63) / 64)
__global__ void k_gat1(const int* __restrict__ rowptr, const int* __restrict__ deg,
                       const int* __restrict__ csr_src,
                       const float* __restrict__ p1, const float* __restrict__ w1,
                       const float* __restrict__ a1d,
                       const float* __restrict__ b1, const float* __restrict__ w2,
                       const float* __restrict__ as2, const float* __restrict__ ad2,
                       __half* __restrict__ h2, float* __restrict__ a2s, float* __restrict__ a2d) {
    __shared__ float sm[64][16];      // per-node: 4 heads x {s0,s1,s2,den}
    __shared__ float f1s[4][128];
    int tid = threadIdx.x;
    int wave = tid >> 6, lane = tid & 63;
    int o = lane & 31, half = lane >> 5;
    int k0 = half * 64;

    // ---- phase A: node = block*64 + wave*16 + (lane>>2); lane&3 = edge phase = head slot
    int nl = wave * 16 + (lane >> 2);
    int h  = lane & 3;
    int n  = blockIdx.x * 64 + nl;
    if (n < N_NODES) {
        float4 ad4 = ((const float4*)a1d)[n];          // broadcast across the quad
        float adv[4] = {ad4.x, ad4.y, ad4.z, ad4.w};
        int beg = rowptr[n], cnt = deg[n];
        float acc[4][4];                                // [head][{s0,s1,s2,den}]
        #pragma unroll
        for (int hh = 0; hh < 4; hh++)
            acc[hh][0] = acc[hh][1] = acc[hh][2] = acc[hh][3] = 0.f;
        int t = h;
        for (; t + 4 < cnt; t += 8) {                   // 2 edges/iter, 4 gathers in flight
            int i0 = csr_src[beg + t], i1 = csr_src[beg + t + 4];
            float4 A0 = ((const float4*)p1)[i0 * 2], X0 = ((const float4*)p1)[i0 * 2 + 1];
            float4 A1 = ((const float4*)p1)[i1 * 2], X1 = ((const float4*)p1)[i1 * 2 + 1];
            float a0v[4] = {A0.x, A0.y, A0.z, A0.w};
            float a1v[4] = {A1.x, A1.y, A1.z, A1.w};
            #pragma unroll
            for (int hh = 0; hh < 4; hh++) {
                float e0 = __expf(lrelu(a0v[hh] + adv[hh]));
                float e1 = __expf(lrelu(a1v[hh] + adv[hh]));
                acc[hh][0] += e0 * X0.x + e1 * X1.x;
                acc[hh][1] += e0 * X0.y + e1 * X1.y;
                acc[hh][2] += e0 * X0.z + e1 * X1.z;
                acc[hh][3] += e0 + e1;
            }
        }
        if (t < cnt) {                                  // at most 1 tail edge per lane
            int i0 = csr_src[beg + t];
            float4 A0 = ((const float4*)p1)[i0 * 2], X0 = ((const float4*)p1)[i0 * 2 + 1];
            float a0v[4] = {A0.x, A0.y, A0.z, A0.w};
            #pragma unroll
            for (int hh = 0; hh < 4; hh++) {
                float e0 = __expf(lrelu(a0v[hh] + adv[hh]));
                acc[hh][0] += e0 * X0.x;
                acc[hh][1] += e0 * X0.y;
                acc[hh][2] += e0 * X0.z;
                acc[hh][3] += e0;
            }
        }
        // 4-lane butterfly (quad is exec-uniform: same n) — every lane gets full sums
        #pragma unroll
        for (int hh = 0; hh < 4; hh++) {
            #pragma unroll
            for (int cc = 0; cc < 4; cc++) {
                float vv = acc[hh][cc];
                vv += __shfl_xor(vv, 1);
                vv += __shfl_xor(vv, 2);
                acc[hh][cc] = vv;
            }
        }
        float4 r;   // lane writes its own head's slice (static-index select, once per node)
        r.x = h == 0 ? acc[0][0] : h == 1 ? acc[1][0] : h == 2 ? acc[2][0] : acc[3][0];
        r.y = h == 0 ? acc[0][1] : h == 1 ? acc[1][1] : h == 2 ? acc[2][1] : acc[3][1];
        r.z = h == 0 ? acc[0][2] : h == 1 ? acc[1][2] : h == 2 ? acc[2][2] : acc[3][2];
        r.w = h == 0 ? acc[0][3] : h == 1 ? acc[1][3] : h == 2 ? acc[2][3] : acc[3][3];
        *(float4*)&sm[nl][h * 4] = r;
    }
    // same-wave LDS write->read below: no barrier needed

    // per-lane w2 column loaded AFTER phase A (keeps gather-loop VGPR pressure low)
    float w2r[64];
    {
        const float4* wp = (const float4*)(w2 + o * 128 + k0);
        #pragma unroll
        for (int q = 0; q < 16; q++) {
            float4 t = wp[q];
            w2r[q * 4 + 0] = t.x; w2r[q * 4 + 1] = t.y;
            w2r[q * 4 + 2] = t.z; w2r[q * 4 + 3] = t.w;
        }
    }

    // ---- phase B: wave processes its own 16 nodes
    int j = lane, j2 = lane + 64;
    int h0 = j >> 5;
    float wa0 = w1[j * 3], wa1 = w1[j * 3 + 1], wa2 = w1[j * 3 + 2];
    float wb0 = w1[j2 * 3], wb1 = w1[j2 * 3 + 1], wb2 = w1[j2 * 3 + 2];
    float b1j = b1[j], b1j2 = b1[j2];
    float as2o = as2[o], ad2o = ad2[o];
    const float* f = f1s[wave];

    #pragma unroll 1
    for (int i = 0; i < 16; i++) {
        int n2 = blockIdx.x * 64 + wave * 16 + i;
        if (n2 >= N_NODES) break;
        const float* S = sm[wave * 16 + i];
        float v0 = (wa0 * S[h0 * 4] + wa1 * S[h0 * 4 + 1] + wa2 * S[h0 * 4 + 2])
                   / (S[h0 * 4 + 3] + EPS) + b1j;
        float v1 = (wb0 * S[(2 + h0) * 4] + wb1 * S[(2 + h0) * 4 + 1] + wb2 * S[(2 + h0) * 4 + 2])
                   / (S[(2 + h0) * 4 + 3] + EPS) + b1j2;
        f1s[wave][j]  = v0 > 0.f ? v0 : expm1f(v0);
        f1s[wave][j2] = v1 > 0.f ? v1 : expm1f(v1);
        float acc = 0.f;
        #pragma unroll
        for (int t = 0; t < 64; t++)
            acc += f[k0 + t] * w2r[t];
        acc += __shfl_down(acc, 32);
        if (half == 0) {
            h2[n2 * 32 + o] = __float2half(acc);   // fp16 row (64 B, coalesced)
            float ps = acc * as2o, pd = acc * ad2o;
            #pragma unroll
            for (int off = 16; off; off >>= 1) {
                ps += __shfl_xor(ps, off);
                pd += __shfl_xor(pd, off);
            }
            if (o == 0) { a2s[n2] = ps; a2d[n2] = pd; }
        }
    }
}

// ---------------------------------------------------------------- K-GAT2 v3: fp16 h2 rows (64 B = 1 line) gathered via ld4h
// wave per node. Lane = (edge-subgroup eg = lane>>3, channel-quad qq = lane&7).
// exp phase: lane owns edge base+lane (1 gather+expf), stages (idx,e) in LDS.
// aggregation: 8 edges/pass, each lane reads pk broadcast + 8 B (4 halfs) of h2.
// Node end: 3-step shfl butterfly (8/16/32) reduces edge-subgroups; lanes 0..7
// hold channel-quad sums -> hfs. Epilogue matvec unchanged.
#define G2_BLOCKS 4096
__global__ void k_gat2(const int* __restrict__ rowptr, const int* __restrict__ deg,
                       const int* __restrict__ csr_src,
                       const __half* __restrict__ h2, const float* __restrict__ a2s,
                       const float* __restrict__ a2d, const float* __restrict__ b2,
                       const float* __restrict__ mw1, const float* __restrict__ mb1,
                       __half* __restrict__ u, __half* __restrict__ v) {
    __shared__ float Ws2[2][32 * 36];    // [half][c*36+k]; row start 144B (16B-aligned)
    __shared__ int2  pk[4][64];          // per-wave staged (idx, e-bits)
    __shared__ float4 hfs[4][8];         // per-wave hf vector (32 floats)
    int tid = threadIdx.x;
    for (int i = tid; i < 2048; i += 256) {
        int c = i >> 6, col = i & 63;
        Ws2[col >> 5][c * 36 + (col & 31)] = mw1[i];
    }
    __syncthreads();
    int lane = tid & 63, w = tid >> 6;
    int qq = lane & 7, eg = lane >> 3;
    int c = lane & 31, half = lane >> 5;
    float4 b2q = ((const float4*)b2)[qq];
    float bias = half ? 0.f : mb1[c];
    __half* outp = half ? v : u;
    const float4* Wr = (const float4*)&Ws2[half][c * 36];
    int wid = blockIdx.x * 4 + w;
    const int stride = G2_BLOCKS * 4;
    for (int n = wid; n < N_NODES; n += stride) {
        float ad = a2d[n];
        int beg = rowptr[n], cnt = deg[n];
        float4 acc4 = make_float4(0.f, 0.f, 0.f, 0.f);
        float den = 0.f;
        for (int base = 0; base < cnt; base += 64) {
            int li = base + lane;
            int idx = (li < cnt) ? csr_src[beg + li] : 0;   // coalesced
            float e = 0.f;
            if (li < cnt) e = __expf(lrelu(a2s[idx] + ad)); // 1 gather+expf per edge
            den += e;
            pk[w][lane] = make_int2(idx, __float_as_int(e)); // same-wave stage (e=0 pads)
            #pragma unroll
            for (int p = 0; p < 8; p++) {
                int2 pe = pk[w][p * 8 + eg];                 // ds_read_b64 broadcast x8 lanes
                float4 g = ld4h(h2 + pe.x * 32 + qq * 4);    // 8-B gather (fp16 row)
                float ee = __int_as_float(pe.y);             // 0 for pad edges
                acc4.x += ee * g.x; acc4.y += ee * g.y;
                acc4.z += ee * g.z; acc4.w += ee * g.w;
            }
        }
        // reduce across edge-subgroups: lanes with same qq, eg in {0..7}
        #pragma unroll
        for (int off = 8; off < 64; off <<= 1) {
            acc4.x += __shfl_xor(acc4.x, off);
            acc4.y += __shfl_xor(acc4.y, off);
            acc4.z += __shfl_xor(acc4.z, off);
            acc4.w += __shfl_xor(acc4.w, off);
        }
        #pragma unroll
        for (int off = 32; off; off >>= 1) den += __shfl_xor(den, off);
        float inv = 1.f / (den + EPS);
        float4 hfc;
        hfc.x = acc4.x * inv + b2q.x;
        hfc.y = acc4.y * inv + b2q.y;
        hfc.z = acc4.z * inv + b2q.z;
        hfc.w = acc4.w * inv + b2q.w;
        if (lane < 8) hfs[w][lane] = hfc;    // lane<8 => eg=0, qq=lane; same-wave stage
        float r = bias;
        #pragma unroll
        for (int q = 0; q < 8; q++) {
            float4 Wq = Wr[q];               // 4-way bank (~1.6x), 8 ops
            float4 hq = hfs[w][q];           // wave-uniform broadcast, free
            r += Wq.x * hq.x + Wq.y * hq.y + Wq.z * hq.z + Wq.w * hq.w;
        }
        outp[n * 32 + c] = __float2half(r);
    }
}

// ---------------------------------------------------------------- K-MLP: 8 lanes/edge, 4 edges/iter, fp16 u/v rows (1 line each)
#define MLP_BLOCKS 4096
__global__ void k_mlp(const int* __restrict__ ei, const __half* __restrict__ u,
                      const __half* __restrict__ v, const float* __restrict__ mw2,
                      const float* __restrict__ mb2, float* __restrict__ out) {
    int tid = threadIdx.x;
    int q = tid & 7;
    float4 w2q = ((const float4*)mw2)[q];
    float mb20 = mb2[0];
    int g = blockIdx.x * 32 + (tid >> 3);
    const int stride = MLP_BLOCKS * 32 * 4;
    for (int e = g * 4; e < N_EDGES; e += stride) {
        int eb = e;
        int e1 = (eb + 1 < N_EDGES) ? eb + 1 : eb;
        int e2 = (eb + 2 < N_EDGES) ? eb + 2 : eb;
        int e3 = (eb + 3 < N_EDGES) ? eb + 3 : eb;
        int sa = ei[eb], da = ei[N_EDGES + eb];
        int sb = ei[e1], db = ei[N_EDGES + e1];
        int sc = ei[e2], dc = ei[N_EDGES + e2];
        int sd = ei[e3], dd = ei[N_EDGES + e3];
        float4 ua = ld4h(u + sa * 32 + q * 4);
        float4 va = ld4h(v + da * 32 + q * 4);
        float4 ub = ld4h(u + sb * 32 + q * 4);
        float4 vb = ld4h(v + db * 32 + q * 4);
        float4 uc = ld4h(u + sc * 32 + q * 4);
        float4 vc = ld4h(v + dc * 32 + q * 4);
        float4 ud = ld4h(u + sd * 32 + q * 4);
        float4 vd = ld4h(v + dd * 32 + q * 4);
        float s0 = fmaxf(ua.x + va.x, 0.f) * w2q.x + fmaxf(ua.y + va.y, 0.f) * w2q.y
                 + fmaxf(ua.z + va.z, 0.f) * w2q.z + fmaxf(ua.w + va.w, 0.f) * w2q.w;
        float s1 = fmaxf(ub.x + vb.x, 0.f) * w2q.x + fmaxf(ub.y + vb.y, 0.f) * w2q.y
                 + fmaxf(ub.z + vb.z, 0.f) * w2q.z + fmaxf(ub.w + vb.w, 0.f) * w2q.w;
        float s2 = fmaxf(uc.x + vc.x, 0.f) * w2q.x + fmaxf(uc.y + vc.y, 0.f) * w2q.y
                 + fmaxf(uc.z + vc.z, 0.f) * w2q.z + fmaxf(uc.w + vc.w, 0.f) * w2q.w;
        float s3 = fmaxf(ud.x + vd.x, 0.f) * w2q.x + fmaxf(ud.y + vd.y, 0.f) * w2q.y
                 + fmaxf(ud.z + vd.z, 0.f) * w2q.z + fmaxf(ud.w + vd.w, 0.f) * w2q.w;
        s0 += __shfl_xor(s0, 1, 8); s0 += __shfl_xor(s0, 2, 8); s0 += __shfl_xor(s0, 4, 8);
        s1 += __shfl_xor(s1, 1, 8); s1 += __shfl_xor(s1, 2, 8); s1 += __shfl_xor(s1, 4, 8);
        s2 += __shfl_xor(s2, 1, 8); s2 += __shfl_xor(s2, 2, 8); s2 += __shfl_xor(s2, 4, 8);
        s3 += __shfl_xor(s3, 1, 8); s3 += __shfl_xor(s3, 2, 8); s3 += __shfl_xor(s3, 4, 8);
        if (q == 0) {
            out[eb] = fmaxf(s0 + mb20, 0.f);
            if (eb + 1 < N_EDGES) out[eb + 1] = fmaxf(s1 + mb20, 0.f);
            if (eb + 2 < N_EDGES) out[eb + 2] = fmaxf(s2 + mb20, 0.f);
            if (eb + 3 < N_EDGES) out[eb + 3] = fmaxf(s3 + mb20, 0.f);
        }
    }
}

// ---------------------------------------------------------------- launch
extern "C" void kernel_launch(void* const* d_in, const int* in_sizes, int n_in,
                              void* d_out, int out_size, void* d_ws, size_t ws_size,
                              hipStream_t stream) {
    const float* x    = (const float*)d_in[0];
    const int*   ei   = (const int*)d_in[1];
    const float* w1   = (const float*)d_in[2];
    const float* as1  = (const float*)d_in[3];
    const float* ad1  = (const float*)d_in[4];
    const float* b1   = (const float*)d_in[5];
    const float* w2   = (const float*)d_in[6];
    const float* as2  = (const float*)d_in[7];
    const float* ad2  = (const float*)d_in[8];
    const float* b2   = (const float*)d_in[9];
    const float* mw1  = (const float*)d_in[10];
    const float* mb1  = (const float*)d_in[11];
    const float* mw2  = (const float*)d_in[12];
    const float* mb2  = (const float*)d_in[13];
    float* out = (float*)d_out;

    const int N = N_NODES;
    // byte-offset workspace layout; p1/h2/u/v 64B-aligned (offsets verified)
    char* base   = (char*)d_ws;
    int* deg     = (int*)(base);                      // N*4
    int* rowptr  = (int*)(base + 400000);             // N*4
    int* bstart  = (int*)(base + 800000);             // (NBUCK+1)*4 = 788 B
    int* bh      = (int*)(base + 1200000);            // BLKB*NBUCK*4 = 306,544 B
    int* csr_src = (int*)(base + 1602048);            // E*4
    float* p1    = (float*)(base + 8002048);          // 8N*4   (%64==0)
    float* a1d   = (float*)(base + 11202048);         // 4N*4
    __half* h2   = (__half*)(base + 12802048);        // 32N*2  (%64==0)
    int* binned  = (int*)(base + 19202048);           // E*4 (disjoint lifetime vs h2 region tail)
    float* a2s   = (float*)(base + 25602048);         // N*4
    float* a2d   = (float*)(base + 26002048);         // N*4
    __half* u    = (__half*)(base + 26402048);        // 32N*2  (%64==0)
    __half* v    = (__half*)(base + 32802048);        // 32N*2  (%64==0)
    float* qv    = (float*)(base + 39202048);         // 24

    const int nb = (N + 255) / 256;

    kA_hist<<<BLKB, 256, 0, stream>>>(ei, bh);
    kS1<<<NBUCK, 256, 0, stream>>>(bh, bstart);
    kS2<<<1, 256, 0, stream>>>(bstart);
    kB_bin<<<BLKB, 256, 0, stream>>>(ei, bh, bstart, binned);
    kC_sort<<<NBUCK, 256, 0, stream>>>(bstart, binned, deg, rowptr, csr_src);

    k_q<<<1, 32, 0, stream>>>(w1, as1, ad1, qv);
    k_node1<<<nb, 256, 0, stream>>>(x, qv, a1d, p1);

    k_gat1<<<G1_BLOCKS, 256, 0, stream>>>(rowptr, deg, csr_src, p1, w1, a1d,
                                          b1, w2, as2, ad2, h2, a2s, a2d);

    k_gat2<<<G2_BLOCKS, 256, 0, stream>>>(rowptr, deg, csr_src, h2, a2s, a2d, b2,
                                          mw1, mb1, u, v);

    k_mlp<<<MLP_BLOCKS, 256, 0, stream>>>(ei, u, v, mw2, mb2, out);
}

// Round 6
// 303.783 us; speedup vs baseline: 1.3475x; 1.0140x over previous
//
#include <hip/hip_runtime.h>
#include <hip/hip_fp16.h>
#include <math.h>

#define N_NODES 100000
#define N_EDGES 1600000
#define NEG_SLOPE 0.2f
#define EPS 1e-16f

// bucket sort geometry: 196 buckets of 512 nodes; 391 blocks x 4096 edges
#define NBUCK 196
#define CHUNK 4096
#define BLKB 391

__device__ __forceinline__ float lrelu(float v) { return v > 0.f ? v : NEG_SLOPE * v; }

// load 4 halfs -> float4 (single 8B load)
__device__ __forceinline__ float4 ld4h(const __half* p) {
    uint2 r = *(const uint2*)p;
    __half2 h0 = *reinterpret_cast<const __half2*>(&r.x);
    __half2 h1 = *reinterpret_cast<const __half2*>(&r.y);
    float2 f0 = __half22float2(h0), f1 = __half22float2(h1);
    return make_float4(f0.x, f0.y, f1.x, f1.y);
}

// ---------------------------------------------------------------- Pass A: per-block coarse histogram (LDS only)
__global__ void kA_hist(const int* __restrict__ ei, int* __restrict__ bh) {
    __shared__ int hist[NBUCK];
    int tid = threadIdx.x, b = blockIdx.x;
    if (tid < NBUCK) hist[tid] = 0;
    __syncthreads();
    int base = b * CHUNK;
    #pragma unroll
    for (int i = 0; i < CHUNK / 256; i++) {
        int e = base + i * 256 + tid;
        if (e < N_EDGES) {
            int dst = ei[N_EDGES + e];
            atomicAdd(&hist[dst >> 9], 1);
        }
    }
    __syncthreads();
    if (tid < NBUCK) bh[b * NBUCK + tid] = hist[tid];
}

// ---------------------------------------------------------------- S1: column scan of bh (one block per bucket)
__global__ void kS1(int* __restrict__ bh, int* __restrict__ bucketStart) {
    __shared__ int tsum[256];
    int k = blockIdx.x, t = threadIdx.x;
    int j0 = 2 * t, j1 = 2 * t + 1;
    int v0 = (j0 < BLKB) ? bh[j0 * NBUCK + k] : 0;
    int v1 = (j1 < BLKB) ? bh[j1 * NBUCK + k] : 0;
    int s = v0 + v1;
    tsum[t] = s;
    __syncthreads();
    for (int off = 1; off < 256; off <<= 1) {
        int tv = (t >= off) ? tsum[t - off] : 0;
        __syncthreads();
        tsum[t] += tv;
        __syncthreads();
    }
    int excl = tsum[t] - s;
    if (j0 < BLKB) bh[j0 * NBUCK + k] = excl;
    if (j1 < BLKB) bh[j1 * NBUCK + k] = excl + v0;
    if (t == 255) bucketStart[k] = tsum[255];   // column total (scanned by S2)
}

// ---------------------------------------------------------------- S2: scan bucket totals -> bucket starts (+ total at [NBUCK])
__global__ void kS2(int* __restrict__ bucketStart) {
    __shared__ int tmp[256];
    int t = threadIdx.x;
    int v = (t < NBUCK) ? bucketStart[t] : 0;
    tmp[t] = v;
    __syncthreads();
    for (int off = 1; off < 256; off <<= 1) {
        int tv = (t >= off) ? tmp[t - off] : 0;
        __syncthreads();
        tmp[t] += tv;
        __syncthreads();
    }
    if (t < NBUCK) bucketStart[t] = tmp[t] - v;
    if (t == NBUCK - 1) bucketStart[NBUCK] = tmp[t];
}

// ---------------------------------------------------------------- Pass B: bin edges by coarse bucket (LDS cursors, coalesced-run writes)
__global__ void kB_bin(const int* __restrict__ ei, const int* __restrict__ bh,
                       const int* __restrict__ bucketStart, int* __restrict__ binned) {
    __shared__ int cur[NBUCK];
    int tid = threadIdx.x, b = blockIdx.x;
    if (tid < NBUCK) cur[tid] = bucketStart[tid] + bh[b * NBUCK + tid];
    __syncthreads();
    int base = b * CHUNK;
    #pragma unroll
    for (int i = 0; i < CHUNK / 256; i++) {
        int e = base + i * 256 + tid;
        if (e < N_EDGES) {
            int src = ei[e], dst = ei[N_EDGES + e];
            int pos = atomicAdd(&cur[dst >> 9], 1);
            binned[pos] = src | ((dst & 511) << 17);
        }
    }
}

// ---------------------------------------------------------------- Pass C: per-bucket counting sort -> deg, rowptr, csr_src
__global__ void kC_sort(const int* __restrict__ bucketStart, const int* __restrict__ binned,
                        int* __restrict__ deg, int* __restrict__ rowptr,
                        int* __restrict__ csr_src) {
    __shared__ int cnt[512];
    __shared__ int pfx[512];
    __shared__ int bsum[256];
    int t = threadIdx.x, k = blockIdx.x;
    int s0 = bucketStart[k], s1 = bucketStart[k + 1];
    cnt[t] = 0; cnt[t + 256] = 0;
    __syncthreads();
    for (int i = s0 + t; i < s1; i += 256)
        atomicAdd(&cnt[binned[i] >> 17], 1);
    __syncthreads();
    int a0 = cnt[2 * t], a1 = cnt[2 * t + 1];
    int s = a0 + a1;
    bsum[t] = s;
    __syncthreads();
    for (int off = 1; off < 256; off <<= 1) {
        int tv = (t >= off) ? bsum[t - off] : 0;
        __syncthreads();
        bsum[t] += tv;
        __syncthreads();
    }
    int excl = bsum[t] - s;
    pfx[2 * t] = excl;
    pfx[2 * t + 1] = excl + a0;
    int nb0 = k << 9;
    int n0 = nb0 + 2 * t, n1 = nb0 + 2 * t + 1;
    if (n0 < N_NODES) { deg[n0] = a0; rowptr[n0] = s0 + excl; }
    if (n1 < N_NODES) { deg[n1] = a1; rowptr[n1] = s0 + excl + a0; }
    __syncthreads();
    for (int i = s0 + t; i < s1; i += 256) {
        int pkd = binned[i];
        int pos = s0 + atomicAdd(&pfx[pkd >> 17], 1);
        csr_src[pos] = pkd & 0x1FFFF;
    }
}

// ---------------------------------------------------------------- K-Q: qs[h] = W1_h^T a_src_h, qd[h] = W1_h^T a_dst_h  (24 floats)
__global__ void k_q(const float* __restrict__ w1, const float* __restrict__ as1,
                    const float* __restrict__ ad1, float* __restrict__ qv) {
    int t = threadIdx.x;
    if (t >= 24) return;
    int c = t % 3, h = (t / 3) % 4, side = t / 12;
    const float* att = side ? ad1 : as1;
    float acc = 0.f;
    for (int cc = 0; cc < 32; cc++)
        acc += att[h * 32 + cc] * w1[(h * 32 + cc) * 3 + c];
    qv[t] = acc;
}

// ---------------------------------------------------------------- K-NODE1: a1d = x.qd ; p1[n] = {a1s[4], x0,x1,x2,1} (32B row)
__global__ void k_node1(const float* __restrict__ x, const float* __restrict__ qv,
                        float* __restrict__ a1d, float* __restrict__ p1) {
    int n = blockIdx.x * blockDim.x + threadIdx.x;
    if (n >= N_NODES) return;
    float x0 = x[n * 3], x1 = x[n * 3 + 1], x2 = x[n * 3 + 2];
    float4 s, d;
    s.x = x0 * qv[0]  + x1 * qv[1]  + x2 * qv[2];
    s.y = x0 * qv[3]  + x1 * qv[4]  + x2 * qv[5];
    s.z = x0 * qv[6]  + x1 * qv[7]  + x2 * qv[8];
    s.w = x0 * qv[9]  + x1 * qv[10] + x2 * qv[11];
    d.x = x0 * qv[12] + x1 * qv[13] + x2 * qv[14];
    d.y = x0 * qv[15] + x1 * qv[16] + x2 * qv[17];
    d.z = x0 * qv[18] + x1 * qv[19] + x2 * qv[20];
    d.w = x0 * qv[21] + x1 * qv[22] + x2 * qv[23];
    ((float4*)a1d)[n] = d;
    ((float4*)p1)[n * 2]     = s;
    float4 xx; xx.x = x0; xx.y = x1; xx.z = x2; xx.w = 1.f;
    ((float4*)p1)[n * 2 + 1] = xx;
}

// ---------------------------------------------------------------- K-GAT1: linearity trick, w2 in registers, packed p1 gathers
// Phase A v2: 4 lanes/node PARTITION the edge list (stride-4) and each lane
// computes all 4 heads in registers -> 2 gathers/edge instead of 8, no
// per-edge select chain. 16-value 4-lane shfl butterfly once per node.
// h2 stored fp16 (64-B rows).
#define G1_BLOCKS ((N_NODES + 63) / 64)
__global__ void k_gat1(const int* __restrict__ rowptr, const int* __restrict__ deg,
                       const int* __restrict__ csr_src,
                       const float* __restrict__ p1, const float* __restrict__ w1,
                       const float* __restrict__ a1d,
                       const float* __restrict__ b1, const float* __restrict__ w2,
                       const float* __restrict__ as2, const float* __restrict__ ad2,
                       __half* __restrict__ h2, float* __restrict__ a2s, float* __restrict__ a2d) {
    __shared__ float sm[64][16];      // per-node: 4 heads x {s0,s1,s2,den}
    __shared__ float f1s[4][128];
    int tid = threadIdx.x;
    int wave = tid >> 6, lane = tid & 63;
    int o = lane & 31, half = lane >> 5;
    int k0 = half * 64;

    // ---- phase A: node = block*64 + wave*16 + (lane>>2); lane&3 = edge phase = head slot
    int nl = wave * 16 + (lane >> 2);
    int h  = lane & 3;
    int n  = blockIdx.x * 64 + nl;
    if (n < N_NODES) {
        float4 ad4 = ((const float4*)a1d)[n];          // broadcast across the quad
        float adv[4] = {ad4.x, ad4.y, ad4.z, ad4.w};
        int beg = rowptr[n], cnt = deg[n];
        float acc[4][4];                                // [head][{s0,s1,s2,den}]
        #pragma unroll
        for (int hh = 0; hh < 4; hh++)
            acc[hh][0] = acc[hh][1] = acc[hh][2] = acc[hh][3] = 0.f;
        int t = h;
        for (; t + 4 < cnt; t += 8) {                   // 2 edges/iter, 4 gathers in flight
            int i0 = csr_src[beg + t], i1 = csr_src[beg + t + 4];
            float4 A0 = ((const float4*)p1)[i0 * 2], X0 = ((const float4*)p1)[i0 * 2 + 1];
            float4 A1 = ((const float4*)p1)[i1 * 2], X1 = ((const float4*)p1)[i1 * 2 + 1];
            float a0v[4] = {A0.x, A0.y, A0.z, A0.w};
            float a1v[4] = {A1.x, A1.y, A1.z, A1.w};
            #pragma unroll
            for (int hh = 0; hh < 4; hh++) {
                float e0 = __expf(lrelu(a0v[hh] + adv[hh]));
                float e1 = __expf(lrelu(a1v[hh] + adv[hh]));
                acc[hh][0] += e0 * X0.x + e1 * X1.x;
                acc[hh][1] += e0 * X0.y + e1 * X1.y;
                acc[hh][2] += e0 * X0.z + e1 * X1.z;
                acc[hh][3] += e0 + e1;
            }
        }
        if (t < cnt) {                                  // at most 1 tail edge per lane
            int i0 = csr_src[beg + t];
            float4 A0 = ((const float4*)p1)[i0 * 2], X0 = ((const float4*)p1)[i0 * 2 + 1];
            float a0v[4] = {A0.x, A0.y, A0.z, A0.w};
            #pragma unroll
            for (int hh = 0; hh < 4; hh++) {
                float e0 = __expf(lrelu(a0v[hh] + adv[hh]));
                acc[hh][0] += e0 * X0.x;
                acc[hh][1] += e0 * X0.y;
                acc[hh][2] += e0 * X0.z;
                acc[hh][3] += e0;
            }
        }
        // 4-lane butterfly (quad is exec-uniform: same n) — every lane gets full sums
        #pragma unroll
        for (int hh = 0; hh < 4; hh++) {
            #pragma unroll
            for (int cc = 0; cc < 4; cc++) {
                float vv = acc[hh][cc];
                vv += __shfl_xor(vv, 1);
                vv += __shfl_xor(vv, 2);
                acc[hh][cc] = vv;
            }
        }
        float4 r;   // lane writes its own head's slice (static-index select, once per node)
        r.x = h == 0 ? acc[0][0] : h == 1 ? acc[1][0] : h == 2 ? acc[2][0] : acc[3][0];
        r.y = h == 0 ? acc[0][1] : h == 1 ? acc[1][1] : h == 2 ? acc[2][1] : acc[3][1];
        r.z = h == 0 ? acc[0][2] : h == 1 ? acc[1][2] : h == 2 ? acc[2][2] : acc[3][2];
        r.w = h == 0 ? acc[0][3] : h == 1 ? acc[1][3] : h == 2 ? acc[2][3] : acc[3][3];
        *(float4*)&sm[nl][h * 4] = r;
    }
    // same-wave LDS write->read below: no barrier needed

    // per-lane w2 column loaded AFTER phase A (keeps gather-loop VGPR pressure low)
    float w2r[64];
    {
        const float4* wp = (const float4*)(w2 + o * 128 + k0);
        #pragma unroll
        for (int q = 0; q < 16; q++) {
            float4 t = wp[q];
            w2r[q * 4 + 0] = t.x; w2r[q * 4 + 1] = t.y;
            w2r[q * 4 + 2] = t.z; w2r[q * 4 + 3] = t.w;
        }
    }

    // ---- phase B: wave processes its own 16 nodes
    int j = lane, j2 = lane + 64;
    int h0 = j >> 5;
    float wa0 = w1[j * 3], wa1 = w1[j * 3 + 1], wa2 = w1[j * 3 + 2];
    float wb0 = w1[j2 * 3], wb1 = w1[j2 * 3 + 1], wb2 = w1[j2 * 3 + 2];
    float b1j = b1[j], b1j2 = b1[j2];
    float as2o = as2[o], ad2o = ad2[o];
    const float* f = f1s[wave];

    #pragma unroll 1
    for (int i = 0; i < 16; i++) {
        int n2 = blockIdx.x * 64 + wave * 16 + i;
        if (n2 >= N_NODES) break;
        const float* S = sm[wave * 16 + i];
        float v0 = (wa0 * S[h0 * 4] + wa1 * S[h0 * 4 + 1] + wa2 * S[h0 * 4 + 2])
                   / (S[h0 * 4 + 3] + EPS) + b1j;
        float v1 = (wb0 * S[(2 + h0) * 4] + wb1 * S[(2 + h0) * 4 + 1] + wb2 * S[(2 + h0) * 4 + 2])
                   / (S[(2 + h0) * 4 + 3] + EPS) + b1j2;
        f1s[wave][j]  = v0 > 0.f ? v0 : expm1f(v0);
        f1s[wave][j2] = v1 > 0.f ? v1 : expm1f(v1);
        float acc = 0.f;
        #pragma unroll
        for (int t = 0; t < 64; t++)
            acc += f[k0 + t] * w2r[t];
        acc += __shfl_down(acc, 32);
        if (half == 0) {
            h2[n2 * 32 + o] = __float2half(acc);   // fp16 row (64 B, coalesced)
            float ps = acc * as2o, pd = acc * ad2o;
            #pragma unroll
            for (int off = 16; off; off >>= 1) {
                ps += __shfl_xor(ps, off);
                pd += __shfl_xor(pd, off);
            }
            if (o == 0) { a2s[n2] = ps; a2d[n2] = pd; }
        }
    }
}

// ---------------------------------------------------------------- K-GAT2 v4: adaptive gather-iteration count
// v3 issued a FIXED 8 gather iterations per 64-edge chunk; with mean degree 16
// ~75% of gather issues were (idx=0,e=0) pads. v4: iters = ceil(m/8)
// (wave-uniform, scalar branch), strip-mined 4/2/1 to keep 2-4 independent
// gathers in flight (preserves useful MLP; kills pad issues + their unpack VALU).
#define G2_BLOCKS 4096
__global__ void k_gat2(const int* __restrict__ rowptr, const int* __restrict__ deg,
                       const int* __restrict__ csr_src,
                       const __half* __restrict__ h2, const float* __restrict__ a2s,
                       const float* __restrict__ a2d, const float* __restrict__ b2,
                       const float* __restrict__ mw1, const float* __restrict__ mb1,
                       __half* __restrict__ u, __half* __restrict__ v) {
    __shared__ float Ws2[2][32 * 36];    // [half][c*36+k]; row start 144B (16B-aligned)
    __shared__ int2  pk[4][64];          // per-wave staged (idx, e-bits)
    __shared__ float4 hfs[4][8];         // per-wave hf vector (32 floats)
    int tid = threadIdx.x;
    for (int i = tid; i < 2048; i += 256) {
        int c = i >> 6, col = i & 63;
        Ws2[col >> 5][c * 36 + (col & 31)] = mw1[i];
    }
    __syncthreads();
    int lane = tid & 63, w = tid >> 6;
    int qq = lane & 7, eg = lane >> 3;
    int c = lane & 31, half = lane >> 5;
    float4 b2q = ((const float4*)b2)[qq];
    float bias = half ? 0.f : mb1[c];
    __half* outp = half ? v : u;
    const float4* Wr = (const float4*)&Ws2[half][c * 36];
    int wid = blockIdx.x * 4 + w;
    const int stride = G2_BLOCKS * 4;
    for (int n = wid; n < N_NODES; n += stride) {
        float ad = a2d[n];
        int beg = rowptr[n], cnt = deg[n];
        float4 acc4 = make_float4(0.f, 0.f, 0.f, 0.f);
        float den = 0.f;
        for (int base = 0; base < cnt; base += 64) {
            int li = base + lane;
            int idx = (li < cnt) ? csr_src[beg + li] : 0;   // coalesced
            float e = 0.f;
            if (li < cnt) e = __expf(lrelu(a2s[idx] + ad)); // 1 gather+expf per edge
            den += e;
            pk[w][lane] = make_int2(idx, __float_as_int(e)); // same-wave stage (e=0 pads)
            int m = cnt - base; if (m > 64) m = 64;
            int iters = (m + 7) >> 3;                        // wave-uniform: 1..8
            int p = 0;
            for (; p + 3 < iters; p += 4) {                  // 4 gathers in flight
                int2 pe0 = pk[w][(p + 0) * 8 + eg];
                int2 pe1 = pk[w][(p + 1) * 8 + eg];
                int2 pe2 = pk[w][(p + 2) * 8 + eg];
                int2 pe3 = pk[w][(p + 3) * 8 + eg];
                float4 g0 = ld4h(h2 + pe0.x * 32 + qq * 4);
                float4 g1 = ld4h(h2 + pe1.x * 32 + qq * 4);
                float4 g2 = ld4h(h2 + pe2.x * 32 + qq * 4);
                float4 g3 = ld4h(h2 + pe3.x * 32 + qq * 4);
                float e0 = __int_as_float(pe0.y), e1 = __int_as_float(pe1.y);
                float e2 = __int_as_float(pe2.y), e3 = __int_as_float(pe3.y);
                acc4.x += e0 * g0.x + e1 * g1.x + e2 * g2.x + e3 * g3.x;
                acc4.y += e0 * g0.y + e1 * g1.y + e2 * g2.y + e3 * g3.y;
                acc4.z += e0 * g0.z + e1 * g1.z + e2 * g2.z + e3 * g3.z;
                acc4.w += e0 * g0.w + e1 * g1.w + e2 * g2.w + e3 * g3.w;
            }
            for (; p + 1 < iters; p += 2) {                  // 2 gathers in flight
                int2 pe0 = pk[w][(p + 0) * 8 + eg];
                int2 pe1 = pk[w][(p + 1) * 8 + eg];
                float4 g0 = ld4h(h2 + pe0.x * 32 + qq * 4);
                float4 g1 = ld4h(h2 + pe1.x * 32 + qq * 4);
                float e0 = __int_as_float(pe0.y), e1 = __int_as_float(pe1.y);
                acc4.x += e0 * g0.x + e1 * g1.x;
                acc4.y += e0 * g0.y + e1 * g1.y;
                acc4.z += e0 * g0.z + e1 * g1.z;
                acc4.w += e0 * g0.w + e1 * g1.w;
            }
            if (p < iters) {
                int2 pe0 = pk[w][p * 8 + eg];
                float4 g0 = ld4h(h2 + pe0.x * 32 + qq * 4);
                float e0 = __int_as_float(pe0.y);
                acc4.x += e0 * g0.x; acc4.y += e0 * g0.y;
                acc4.z += e0 * g0.z; acc4.w += e0 * g0.w;
            }
        }
        // reduce across edge-subgroups: lanes with same qq, eg in {0..7}
        #pragma unroll
        for (int off = 8; off < 64; off <<= 1) {
            acc4.x += __shfl_xor(acc4.x, off);
            acc4.y += __shfl_xor(acc4.y, off);
            acc4.z += __shfl_xor(acc4.z, off);
            acc4.w += __shfl_xor(acc4.w, off);
        }
        #pragma unroll
        for (int off = 32; off; off >>= 1) den += __shfl_xor(den, off);
        float inv = 1.f / (den + EPS);
        float4 hfc;
        hfc.x = acc4.x * inv + b2q.x;
        hfc.y = acc4.y * inv + b2q.y;
        hfc.z = acc4.z * inv + b2q.z;
        hfc.w = acc4.w * inv + b2q.w;
        if (lane < 8) hfs[w][lane] = hfc;    // lane<8 => eg=0, qq=lane; same-wave stage
        float r = bias;
        #pragma unroll
        for (int q = 0; q < 8; q++) {
            float4 Wq = Wr[q];               // 4-way bank (~1.6x), 8 ops
            float4 hq = hfs[w][q];           // wave-uniform broadcast, free
            r += Wq.x * hq.x + Wq.y * hq.y + Wq.z * hq.z + Wq.w * hq.w;
        }
        outp[n * 32 + c] = __float2half(r);
    }
}

// ---------------------------------------------------------------- K-MLP: 8 lanes/edge, 4 edges/iter, fp16 u/v rows (1 line each)
#define MLP_BLOCKS 4096
__global__ void k_mlp(const int* __restrict__ ei, const __half* __restrict__ u,
                      const __half* __restrict__ v, const float* __restrict__ mw2,
                      const float* __restrict__ mb2, float* __restrict__ out) {
    int tid = threadIdx.x;
    int q = tid & 7;
    float4 w2q = ((const float4*)mw2)[q];
    float mb20 = mb2[0];
    int g = blockIdx.x * 32 + (tid >> 3);
    const int stride = MLP_BLOCKS * 32 * 4;
    for (int e = g * 4; e < N_EDGES; e += stride) {
        int eb = e;
        int e1 = (eb + 1 < N_EDGES) ? eb + 1 : eb;
        int e2 = (eb + 2 < N_EDGES) ? eb + 2 : eb;
        int e3 = (eb + 3 < N_EDGES) ? eb + 3 : eb;
        int sa = ei[eb], da = ei[N_EDGES + eb];
        int sb = ei[e1], db = ei[N_EDGES + e1];
        int sc = ei[e2], dc = ei[N_EDGES + e2];
        int sd = ei[e3], dd = ei[N_EDGES + e3];
        float4 ua = ld4h(u + sa * 32 + q * 4);
        float4 va = ld4h(v + da * 32 + q * 4);
        float4 ub = ld4h(u + sb * 32 + q * 4);
        float4 vb = ld4h(v + db * 32 + q * 4);
        float4 uc = ld4h(u + sc * 32 + q * 4);
        float4 vc = ld4h(v + dc * 32 + q * 4);
        float4 ud = ld4h(u + sd * 32 + q * 4);
        float4 vd = ld4h(v + dd * 32 + q * 4);
        float s0 = fmaxf(ua.x + va.x, 0.f) * w2q.x + fmaxf(ua.y + va.y, 0.f) * w2q.y
                 + fmaxf(ua.z + va.z, 0.f) * w2q.z + fmaxf(ua.w + va.w, 0.f) * w2q.w;
        float s1 = fmaxf(ub.x + vb.x, 0.f) * w2q.x + fmaxf(ub.y + vb.y, 0.f) * w2q.y
                 + fmaxf(ub.z + vb.z, 0.f) * w2q.z + fmaxf(ub.w + vb.w, 0.f) * w2q.w;
        float s2 = fmaxf(uc.x + vc.x, 0.f) * w2q.x + fmaxf(uc.y + vc.y, 0.f) * w2q.y
                 + fmaxf(uc.z + vc.z, 0.f) * w2q.z + fmaxf(uc.w + vc.w, 0.f) * w2q.w;
        float s3 = fmaxf(ud.x + vd.x, 0.f) * w2q.x + fmaxf(ud.y + vd.y, 0.f) * w2q.y
                 + fmaxf(ud.z + vd.z, 0.f) * w2q.z + fmaxf(ud.w + vd.w, 0.f) * w2q.w;
        s0 += __shfl_xor(s0, 1, 8); s0 += __shfl_xor(s0, 2, 8); s0 += __shfl_xor(s0, 4, 8);
        s1 += __shfl_xor(s1, 1, 8); s1 += __shfl_xor(s1, 2, 8); s1 += __shfl_xor(s1, 4, 8);
        s2 += __shfl_xor(s2, 1, 8); s2 += __shfl_xor(s2, 2, 8); s2 += __shfl_xor(s2, 4, 8);
        s3 += __shfl_xor(s3, 1, 8); s3 += __shfl_xor(s3, 2, 8); s3 += __shfl_xor(s3, 4, 8);
        if (q == 0) {
            out[eb] = fmaxf(s0 + mb20, 0.f);
            if (eb + 1 < N_EDGES) out[eb + 1] = fmaxf(s1 + mb20, 0.f);
            if (eb + 2 < N_EDGES) out[eb + 2] = fmaxf(s2 + mb20, 0.f);
            if (eb + 3 < N_EDGES) out[eb + 3] = fmaxf(s3 + mb20, 0.f);
        }
    }
}

// ---------------------------------------------------------------- launch
extern "C" void kernel_launch(void* const* d_in, const int* in_sizes, int n_in,
                              void* d_out, int out_size, void* d_ws, size_t ws_size,
                              hipStream_t stream) {
    const float* x    = (const float*)d_in[0];
    const int*   ei   = (const int*)d_in[1];
    const float* w1   = (const float*)d_in[2];
    const float* as1  = (const float*)d_in[3];
    const float* ad1  = (const float*)d_in[4];
    const float* b1   = (const float*)d_in[5];
    const float* w2   = (const float*)d_in[6];
    const float* as2  = (const float*)d_in[7];
    const float* ad2  = (const float*)d_in[8];
    const float* b2   = (const float*)d_in[9];
    const float* mw1  = (const float*)d_in[10];
    const float* mb1  = (const float*)d_in[11];
    const float* mw2  = (const float*)d_in[12];
    const float* mb2  = (const float*)d_in[13];
    float* out = (float*)d_out;

    const int N = N_NODES;
    // byte-offset workspace layout; p1/h2/u/v 64B-aligned (offsets verified)
    char* base   = (char*)d_ws;
    int* deg     = (int*)(base);                      // N*4
    int* rowptr  = (int*)(base + 400000);             // N*4
    int* bstart  = (int*)(base + 800000);             // (NBUCK+1)*4 = 788 B
    int* bh      = (int*)(base + 1200000);            // BLKB*NBUCK*4 = 306,544 B
    int* csr_src = (int*)(base + 1602048);            // E*4
    float* p1    = (float*)(base + 8002048);          // 8N*4   (%64==0)
    float* a1d   = (float*)(base + 11202048);         // 4N*4
    __half* h2   = (__half*)(base + 12802048);        // 32N*2  (%64==0)
    int* binned  = (int*)(base + 19202048);           // E*4 (disjoint lifetime vs h2 region tail)
    float* a2s   = (float*)(base + 25602048);         // N*4
    float* a2d   = (float*)(base + 26002048);         // N*4
    __half* u    = (__half*)(base + 26402048);        // 32N*2  (%64==0)
    __half* v    = (__half*)(base + 32802048);        // 32N*2  (%64==0)
    float* qv    = (float*)(base + 39202048);         // 24

    const int nb = (N + 255) / 256;

    kA_hist<<<BLKB, 256, 0, stream>>>(ei, bh);
    kS1<<<NBUCK, 256, 0, stream>>>(bh, bstart);
    kS2<<<1, 256, 0, stream>>>(bstart);
    kB_bin<<<BLKB, 256, 0, stream>>>(ei, bh, bstart, binned);
    kC_sort<<<NBUCK, 256, 0, stream>>>(bstart, binned, deg, rowptr, csr_src);

    k_q<<<1, 32, 0, stream>>>(w1, as1, ad1, qv);
    k_node1<<<nb, 256, 0, stream>>>(x, qv, a1d, p1);

    k_gat1<<<G1_BLOCKS, 256, 0, stream>>>(rowptr, deg, csr_src, p1, w1, a1d,
                                          b1, w2, as2, ad2, h2, a2s, a2d);

    k_gat2<<<G2_BLOCKS, 256, 0, stream>>>(rowptr, deg, csr_src, h2, a2s, a2d, b2,
                                          mw1, mb1, u, v);

    k_mlp<<<MLP_BLOCKS, 256, 0, stream>>>(ei, u, v, mw2, mb2, out);
}

// Round 7
// 284.479 us; speedup vs baseline: 1.4390x; 1.0679x over previous
//
#include <hip/hip_runtime.h>
#include <hip/hip_fp16.h>
#include <math.h>

#define N_NODES 100000
#define N_EDGES 1600000
#define NEG_SLOPE 0.2f
#define EPS 1e-16f

// bucket sort geometry: 196 buckets of 512 nodes; 391 blocks x 4096 edges
#define NBUCK 196
#define CHUNK 4096
#define BLKB 391

__device__ __forceinline__ float lrelu(float v) { return v > 0.f ? v : NEG_SLOPE * v; }

// load 4 halfs -> float4 (single 8B load)
__device__ __forceinline__ float4 ld4h(const __half* p) {
    uint2 r = *(const uint2*)p;
    __half2 h0 = *reinterpret_cast<const __half2*>(&r.x);
    __half2 h1 = *reinterpret_cast<const __half2*>(&r.y);
    float2 f0 = __half22float2(h0), f1 = __half22float2(h1);
    return make_float4(f0.x, f0.y, f1.x, f1.y);
}

// load 8 halfs -> 8 floats (single 16B load)
__device__ __forceinline__ void ld8h(const __half* p, float* f) {
    uint4 r = *(const uint4*)p;
    __half2 h0 = *reinterpret_cast<const __half2*>(&r.x);
    __half2 h1 = *reinterpret_cast<const __half2*>(&r.y);
    __half2 h2 = *reinterpret_cast<const __half2*>(&r.z);
    __half2 h3 = *reinterpret_cast<const __half2*>(&r.w);
    float2 f0 = __half22float2(h0), f1 = __half22float2(h1);
    float2 f2 = __half22float2(h2), f3 = __half22float2(h3);
    f[0] = f0.x; f[1] = f0.y; f[2] = f1.x; f[3] = f1.y;
    f[4] = f2.x; f[5] = f2.y; f[6] = f3.x; f[7] = f3.y;
}

// ---------------------------------------------------------------- Pass A: per-block coarse histogram (LDS only)
__global__ void kA_hist(const int* __restrict__ ei, int* __restrict__ bh) {
    __shared__ int hist[NBUCK];
    int tid = threadIdx.x, b = blockIdx.x;
    if (tid < NBUCK) hist[tid] = 0;
    __syncthreads();
    int base = b * CHUNK;
    #pragma unroll
    for (int i = 0; i < CHUNK / 256; i++) {
        int e = base + i * 256 + tid;
        if (e < N_EDGES) {
            int dst = ei[N_EDGES + e];
            atomicAdd(&hist[dst >> 9], 1);
        }
    }
    __syncthreads();
    if (tid < NBUCK) bh[b * NBUCK + tid] = hist[tid];
}

// ---------------------------------------------------------------- S1: column scan of bh (one block per bucket)
__global__ void kS1(int* __restrict__ bh, int* __restrict__ bucketStart) {
    __shared__ int tsum[256];
    int k = blockIdx.x, t = threadIdx.x;
    int j0 = 2 * t, j1 = 2 * t + 1;
    int v0 = (j0 < BLKB) ? bh[j0 * NBUCK + k] : 0;
    int v1 = (j1 < BLKB) ? bh[j1 * NBUCK + k] : 0;
    int s = v0 + v1;
    tsum[t] = s;
    __syncthreads();
    for (int off = 1; off < 256; off <<= 1) {
        int tv = (t >= off) ? tsum[t - off] : 0;
        __syncthreads();
        tsum[t] += tv;
        __syncthreads();
    }
    int excl = tsum[t] - s;
    if (j0 < BLKB) bh[j0 * NBUCK + k] = excl;
    if (j1 < BLKB) bh[j1 * NBUCK + k] = excl + v0;
    if (t == 255) bucketStart[k] = tsum[255];   // column total (scanned by S2)
}

// ---------------------------------------------------------------- S2: scan bucket totals -> bucket starts (+ total at [NBUCK])
__global__ void kS2(int* __restrict__ bucketStart) {
    __shared__ int tmp[256];
    int t = threadIdx.x;
    int v = (t < NBUCK) ? bucketStart[t] : 0;
    tmp[t] = v;
    __syncthreads();
    for (int off = 1; off < 256; off <<= 1) {
        int tv = (t >= off) ? tmp[t - off] : 0;
        __syncthreads();
        tmp[t] += tv;
        __syncthreads();
    }
    if (t < NBUCK) bucketStart[t] = tmp[t] - v;
    if (t == NBUCK - 1) bucketStart[NBUCK] = tmp[t];
}

// ---------------------------------------------------------------- Pass B: bin edges by coarse bucket (LDS cursors, coalesced-run writes)
__global__ void kB_bin(const int* __restrict__ ei, const int* __restrict__ bh,
                       const int* __restrict__ bucketStart, int* __restrict__ binned) {
    __shared__ int cur[NBUCK];
    int tid = threadIdx.x, b = blockIdx.x;
    if (tid < NBUCK) cur[tid] = bucketStart[tid] + bh[b * NBUCK + tid];
    __syncthreads();
    int base = b * CHUNK;
    #pragma unroll
    for (int i = 0; i < CHUNK / 256; i++) {
        int e = base + i * 256 + tid;
        if (e < N_EDGES) {
            int src = ei[e], dst = ei[N_EDGES + e];
            int pos = atomicAdd(&cur[dst >> 9], 1);
            binned[pos] = src | ((dst & 511) << 17);
        }
    }
}

// ---------------------------------------------------------------- Pass C: per-bucket counting sort -> deg, rowptr, csr_src
__global__ void kC_sort(const int* __restrict__ bucketStart, const int* __restrict__ binned,
                        int* __restrict__ deg, int* __restrict__ rowptr,
                        int* __restrict__ csr_src) {
    __shared__ int cnt[512];
    __shared__ int pfx[512];
    __shared__ int bsum[256];
    int t = threadIdx.x, k = blockIdx.x;
    int s0 = bucketStart[k], s1 = bucketStart[k + 1];
    cnt[t] = 0; cnt[t + 256] = 0;
    __syncthreads();
    for (int i = s0 + t; i < s1; i += 256)
        atomicAdd(&cnt[binned[i] >> 17], 1);
    __syncthreads();
    int a0 = cnt[2 * t], a1 = cnt[2 * t + 1];
    int s = a0 + a1;
    bsum[t] = s;
    __syncthreads();
    for (int off = 1; off < 256; off <<= 1) {
        int tv = (t >= off) ? bsum[t - off] : 0;
        __syncthreads();
        bsum[t] += tv;
        __syncthreads();
    }
    int excl = bsum[t] - s;
    pfx[2 * t] = excl;
    pfx[2 * t + 1] = excl + a0;
    int nb0 = k << 9;
    int n0 = nb0 + 2 * t, n1 = nb0 + 2 * t + 1;
    if (n0 < N_NODES) { deg[n0] = a0; rowptr[n0] = s0 + excl; }
    if (n1 < N_NODES) { deg[n1] = a1; rowptr[n1] = s0 + excl + a0; }
    __syncthreads();
    for (int i = s0 + t; i < s1; i += 256) {
        int pkd = binned[i];
        int pos = s0 + atomicAdd(&pfx[pkd >> 17], 1);
        csr_src[pos] = pkd & 0x1FFFF;
    }
}

// ---------------------------------------------------------------- K-Q: qs[h] = W1_h^T a_src_h, qd[h] = W1_h^T a_dst_h  (24 floats)
__global__ void k_q(const float* __restrict__ w1, const float* __restrict__ as1,
                    const float* __restrict__ ad1, float* __restrict__ qv) {
    int t = threadIdx.x;
    if (t >= 24) return;
    int c = t % 3, h = (t / 3) % 4, side = t / 12;
    const float* att = side ? ad1 : as1;
    float acc = 0.f;
    for (int cc = 0; cc < 32; cc++)
        acc += att[h * 32 + cc] * w1[(h * 32 + cc) * 3 + c];
    qv[t] = acc;
}

// ---------------------------------------------------------------- K-NODE1: a1d = x.qd ; p1[n] = {a1s[4], x0,x1,x2,1} (32B row)
__global__ void k_node1(const float* __restrict__ x, const float* __restrict__ qv,
                        float* __restrict__ a1d, float* __restrict__ p1) {
    int n = blockIdx.x * blockDim.x + threadIdx.x;
    if (n >= N_NODES) return;
    float x0 = x[n * 3], x1 = x[n * 3 + 1], x2 = x[n * 3 + 2];
    float4 s, d;
    s.x = x0 * qv[0]  + x1 * qv[1]  + x2 * qv[2];
    s.y = x0 * qv[3]  + x1 * qv[4]  + x2 * qv[5];
    s.z = x0 * qv[6]  + x1 * qv[7]  + x2 * qv[8];
    s.w = x0 * qv[9]  + x1 * qv[10] + x2 * qv[11];
    d.x = x0 * qv[12] + x1 * qv[13] + x2 * qv[14];
    d.y = x0 * qv[15] + x1 * qv[16] + x2 * qv[17];
    d.z = x0 * qv[18] + x1 * qv[19] + x2 * qv[20];
    d.w = x0 * qv[21] + x1 * qv[22] + x2 * qv[23];
    ((float4*)a1d)[n] = d;
    ((float4*)p1)[n * 2]     = s;
    float4 xx; xx.x = x0; xx.y = x1; xx.z = x2; xx.w = 1.f;
    ((float4*)p1)[n * 2 + 1] = xx;
}

// ---------------------------------------------------------------- K-GAT1: linearity trick, w2 in registers, packed p1 gathers
// Phase A v2: 4 lanes/node PARTITION the edge list (stride-4) and each lane
// computes all 4 heads in registers -> 2 gathers/edge instead of 8, no
// per-edge select chain. 16-value 4-lane shfl butterfly once per node.
// h2 stored fp16 (64-B rows).
#define G1_BLOCKS ((N_NODES + 63) / 64)
__global__ void k_gat1(const int* __restrict__ rowptr, const int* __restrict__ deg,
                       const int* __restrict__ csr_src,
                       const float* __restrict__ p1, const float* __restrict__ w1,
                       const float* __restrict__ a1d,
                       const float* __restrict__ b1, const float* __restrict__ w2,
                       const float* __restrict__ as2, const float* __restrict__ ad2,
                       __half* __restrict__ h2, float* __restrict__ a2s, float* __restrict__ a2d) {
    __shared__ float sm[64][16];      // per-node: 4 heads x {s0,s1,s2,den}
    __shared__ float f1s[4][128];
    int tid = threadIdx.x;
    int wave = tid >> 6, lane = tid & 63;
    int o = lane & 31, half = lane >> 5;
    int k0 = half * 64;

    // ---- phase A: node = block*64 + wave*16 + (lane>>2); lane&3 = edge phase = head slot
    int nl = wave * 16 + (lane >> 2);
    int h  = lane & 3;
    int n  = blockIdx.x * 64 + nl;
    if (n < N_NODES) {
        float4 ad4 = ((const float4*)a1d)[n];          // broadcast across the quad
        float adv[4] = {ad4.x, ad4.y, ad4.z, ad4.w};
        int beg = rowptr[n], cnt = deg[n];
        float acc[4][4];                                // [head][{s0,s1,s2,den}]
        #pragma unroll
        for (int hh = 0; hh < 4; hh++)
            acc[hh][0] = acc[hh][1] = acc[hh][2] = acc[hh][3] = 0.f;
        int t = h;
        for (; t + 4 < cnt; t += 8) {                   // 2 edges/iter, 4 gathers in flight
            int i0 = csr_src[beg + t], i1 = csr_src[beg + t + 4];
            float4 A0 = ((const float4*)p1)[i0 * 2], X0 = ((const float4*)p1)[i0 * 2 + 1];
            float4 A1 = ((const float4*)p1)[i1 * 2], X1 = ((const float4*)p1)[i1 * 2 + 1];
            float a0v[4] = {A0.x, A0.y, A0.z, A0.w};
            float a1v[4] = {A1.x, A1.y, A1.z, A1.w};
            #pragma unroll
            for (int hh = 0; hh < 4; hh++) {
                float e0 = __expf(lrelu(a0v[hh] + adv[hh]));
                float e1 = __expf(lrelu(a1v[hh] + adv[hh]));
                acc[hh][0] += e0 * X0.x + e1 * X1.x;
                acc[hh][1] += e0 * X0.y + e1 * X1.y;
                acc[hh][2] += e0 * X0.z + e1 * X1.z;
                acc[hh][3] += e0 + e1;
            }
        }
        if (t < cnt) {                                  // at most 1 tail edge per lane
            int i0 = csr_src[beg + t];
            float4 A0 = ((const float4*)p1)[i0 * 2], X0 = ((const float4*)p1)[i0 * 2 + 1];
            float a0v[4] = {A0.x, A0.y, A0.z, A0.w};
            #pragma unroll
            for (int hh = 0; hh < 4; hh++) {
                float e0 = __expf(lrelu(a0v[hh] + adv[hh]));
                acc[hh][0] += e0 * X0.x;
                acc[hh][1] += e0 * X0.y;
                acc[hh][2] += e0 * X0.z;
                acc[hh][3] += e0;
            }
        }
        // 4-lane butterfly (quad is exec-uniform: same n) — every lane gets full sums
        #pragma unroll
        for (int hh = 0; hh < 4; hh++) {
            #pragma unroll
            for (int cc = 0; cc < 4; cc++) {
                float vv = acc[hh][cc];
                vv += __shfl_xor(vv, 1);
                vv += __shfl_xor(vv, 2);
                acc[hh][cc] = vv;
            }
        }
        float4 r;   // lane writes its own head's slice (static-index select, once per node)
        r.x = h == 0 ? acc[0][0] : h == 1 ? acc[1][0] : h == 2 ? acc[2][0] : acc[3][0];
        r.y = h == 0 ? acc[0][1] : h == 1 ? acc[1][1] : h == 2 ? acc[2][1] : acc[3][1];
        r.z = h == 0 ? acc[0][2] : h == 1 ? acc[1][2] : h == 2 ? acc[2][2] : acc[3][2];
        r.w = h == 0 ? acc[0][3] : h == 1 ? acc[1][3] : h == 2 ? acc[2][3] : acc[3][3];
        *(float4*)&sm[nl][h * 4] = r;
    }
    // same-wave LDS write->read below: no barrier needed

    // per-lane w2 column loaded AFTER phase A (keeps gather-loop VGPR pressure low)
    float w2r[64];
    {
        const float4* wp = (const float4*)(w2 + o * 128 + k0);
        #pragma unroll
        for (int q = 0; q < 16; q++) {
            float4 t = wp[q];
            w2r[q * 4 + 0] = t.x; w2r[q * 4 + 1] = t.y;
            w2r[q * 4 + 2] = t.z; w2r[q * 4 + 3] = t.w;
        }
    }

    // ---- phase B: wave processes its own 16 nodes
    int j = lane, j2 = lane + 64;
    int h0 = j >> 5;
    float wa0 = w1[j * 3], wa1 = w1[j * 3 + 1], wa2 = w1[j * 3 + 2];
    float wb0 = w1[j2 * 3], wb1 = w1[j2 * 3 + 1], wb2 = w1[j2 * 3 + 2];
    float b1j = b1[j], b1j2 = b1[j2];
    float as2o = as2[o], ad2o = ad2[o];
    const float* f = f1s[wave];

    #pragma unroll 1
    for (int i = 0; i < 16; i++) {
        int n2 = blockIdx.x * 64 + wave * 16 + i;
        if (n2 >= N_NODES) break;
        const float* S = sm[wave * 16 + i];
        float v0 = (wa0 * S[h0 * 4] + wa1 * S[h0 * 4 + 1] + wa2 * S[h0 * 4 + 2])
                   / (S[h0 * 4 + 3] + EPS) + b1j;
        float v1 = (wb0 * S[(2 + h0) * 4] + wb1 * S[(2 + h0) * 4 + 1] + wb2 * S[(2 + h0) * 4 + 2])
                   / (S[(2 + h0) * 4 + 3] + EPS) + b1j2;
        f1s[wave][j]  = v0 > 0.f ? v0 : expm1f(v0);
        f1s[wave][j2] = v1 > 0.f ? v1 : expm1f(v1);
        float acc = 0.f;
        #pragma unroll
        for (int t = 0; t < 64; t++)
            acc += f[k0 + t] * w2r[t];
        acc += __shfl_down(acc, 32);
        if (half == 0) {
            h2[n2 * 32 + o] = __float2half(acc);   // fp16 row (64 B, coalesced)
            float ps = acc * as2o, pd = acc * ad2o;
            #pragma unroll
            for (int off = 16; off; off >>= 1) {
                ps += __shfl_xor(ps, off);
                pd += __shfl_xor(pd, off);
            }
            if (o == 0) { a2s[n2] = ps; a2d[n2] = pd; }
        }
    }
}

// ---------------------------------------------------------------- K-GAT2 v5: 16 lanes/node, 4 nodes/wave (4x miss chains)
// v4 showed issue-count cuts don't help: latency x concurrency bound.
// v5 multiplies independent gather chains: each 16-lane group owns one node.
// Group layout: eg2 = sl>>2 (4 edge slots), qq = sl&3 (4 x 16-B row chunks).
// Fixed 4-step unrolled gather (pads hit hot line, free per v4 lesson):
// up to 16 rows in flight per wave (vs ~2-4 in v4). Epilogue matvec by the
// group's 16 lanes (4 output channels each, same total LDS ops).
#define G2_BLOCKS ((N_NODES + 15) / 16)
__global__ void k_gat2(const int* __restrict__ rowptr, const int* __restrict__ deg,
                       const int* __restrict__ csr_src,
                       const __half* __restrict__ h2, const float* __restrict__ a2s,
                       const float* __restrict__ a2d, const float* __restrict__ b2,
                       const float* __restrict__ mw1, const float* __restrict__ mb1,
                       __half* __restrict__ u, __half* __restrict__ v) {
    __shared__ float Ws2[2][32 * 36];    // [half][c*36+k]; row start 144B (16B-aligned)
    __shared__ int2  pk[4][64];          // per-wave staged (idx, e-bits), 16 slots/group
    __shared__ float4 hfs[4][4][8];      // [wave][group][8 quads] = hf vector (32 floats)
    int tid = threadIdx.x;
    for (int i = tid; i < 2048; i += 256) {
        int c = i >> 6, col = i & 63;
        Ws2[col >> 5][c * 36 + (col & 31)] = mw1[i];
    }
    __syncthreads();
    int lane = tid & 63, w = tid >> 6;
    int nl = lane >> 4, sl = lane & 15;          // group (node) / sub-lane
    int eg2 = sl >> 2, qq = sl & 3;              // edge slot / 16-B chunk
    int n = blockIdx.x * 16 + w * 4 + nl;        // one node per group, no stride loop
    float4 b2a = ((const float4*)b2)[qq * 2];    // channels qq*8 .. qq*8+3
    float4 b2b = ((const float4*)b2)[qq * 2 + 1];// channels qq*8+4 .. qq*8+7

    int beg = 0, cnt = 0;
    float ad = 0.f;
    if (n < N_NODES) { beg = rowptr[n]; cnt = deg[n]; ad = a2d[n]; }

    float acc[8] = {0.f, 0.f, 0.f, 0.f, 0.f, 0.f, 0.f, 0.f};
    float den = 0.f;
    int pkbase = (nl << 4);
    for (int b16 = 0; b16 < cnt; b16 += 16) {    // group-divergent, exec-masked
        int li = b16 + sl;
        int idx = (li < cnt) ? csr_src[beg + li] : 0;
        float e = 0.f;
        if (li < cnt) e = __expf(lrelu(a2s[idx] + ad));
        den += e;
        pk[w][pkbase + sl] = make_int2(idx, __float_as_int(e)); // same-wave stage
        #pragma unroll
        for (int p = 0; p < 4; p++) {            // fixed 4 steps: 4 rows in flight/group
            int2 pe = pk[w][pkbase + p * 4 + eg2];
            float g[8];
            ld8h(h2 + pe.x * 32 + qq * 8, g);    // 16-B gather (8 halfs)
            float ee = __int_as_float(pe.y);     // 0 for pads
            acc[0] += ee * g[0]; acc[1] += ee * g[1];
            acc[2] += ee * g[2]; acc[3] += ee * g[3];
            acc[4] += ee * g[4]; acc[5] += ee * g[5];
            acc[6] += ee * g[6]; acc[7] += ee * g[7];
        }
    }
    // reduce across the 4 edge slots (within 16-lane group)
    #pragma unroll
    for (int j = 0; j < 8; j++) {
        float vv = acc[j];
        vv += __shfl_xor(vv, 4);
        vv += __shfl_xor(vv, 8);
        acc[j] = vv;
    }
    den += __shfl_xor(den, 1); den += __shfl_xor(den, 2);
    den += __shfl_xor(den, 4); den += __shfl_xor(den, 8);
    float inv = 1.f / (den + EPS);
    if (sl < 4) {                                // sl<4 => eg2=0, qq=sl
        float4 ha, hb;
        ha.x = acc[0] * inv + b2a.x; ha.y = acc[1] * inv + b2a.y;
        ha.z = acc[2] * inv + b2a.z; ha.w = acc[3] * inv + b2a.w;
        hb.x = acc[4] * inv + b2b.x; hb.y = acc[5] * inv + b2b.y;
        hb.z = acc[6] * inv + b2b.z; hb.w = acc[7] * inv + b2b.w;
        hfs[w][nl][qq * 2]     = ha;             // same-wave stage
        hfs[w][nl][qq * 2 + 1] = hb;
    }
    // epilogue: 16 lanes per node, 4 output channels per lane
    if (n < N_NODES) {
        int half_o = sl >> 3, c4 = (sl & 7) * 4;
        __half* outp = half_o ? v : u;
        float r0 = half_o ? 0.f : mb1[c4 + 0];
        float r1 = half_o ? 0.f : mb1[c4 + 1];
        float r2 = half_o ? 0.f : mb1[c4 + 2];
        float r3 = half_o ? 0.f : mb1[c4 + 3];
        const float* Wb = &Ws2[half_o][0];
        #pragma unroll
        for (int q = 0; q < 8; q++) {
            float4 hq = hfs[w][nl][q];           // broadcast within group
            float4 W0 = *(const float4*)&Wb[(c4 + 0) * 36 + q * 4];
            float4 W1 = *(const float4*)&Wb[(c4 + 1) * 36 + q * 4];
            float4 W2 = *(const float4*)&Wb[(c4 + 2) * 36 + q * 4];
            float4 W3 = *(const float4*)&Wb[(c4 + 3) * 36 + q * 4];
            r0 += W0.x * hq.x + W0.y * hq.y + W0.z * hq.z + W0.w * hq.w;
            r1 += W1.x * hq.x + W1.y * hq.y + W1.z * hq.z + W1.w * hq.w;
            r2 += W2.x * hq.x + W2.y * hq.y + W2.z * hq.z + W2.w * hq.w;
            r3 += W3.x * hq.x + W3.y * hq.y + W3.z * hq.z + W3.w * hq.w;
        }
        __half2 p0, p1;
        p0.x = __float2half(r0); p0.y = __float2half(r1);
        p1.x = __float2half(r2); p1.y = __float2half(r3);
        uint2 st;
        st.x = *reinterpret_cast<unsigned int*>(&p0);
        st.y = *reinterpret_cast<unsigned int*>(&p1);
        *reinterpret_cast<uint2*>(outp + n * 32 + c4) = st;  // 8-B aligned store
    }
}

// ---------------------------------------------------------------- K-MLP: 8 lanes/edge, 4 edges/iter, fp16 u/v rows (1 line each)
#define MLP_BLOCKS 4096
__global__ void k_mlp(const int* __restrict__ ei, const __half* __restrict__ u,
                      const __half* __restrict__ v, const float* __restrict__ mw2,
                      const float* __restrict__ mb2, float* __restrict__ out) {
    int tid = threadIdx.x;
    int q = tid & 7;
    float4 w2q = ((const float4*)mw2)[q];
    float mb20 = mb2[0];
    int g = blockIdx.x * 32 + (tid >> 3);
    const int stride = MLP_BLOCKS * 32 * 4;
    for (int e = g * 4; e < N_EDGES; e += stride) {
        int eb = e;
        int e1 = (eb + 1 < N_EDGES) ? eb + 1 : eb;
        int e2 = (eb + 2 < N_EDGES) ? eb + 2 : eb;
        int e3 = (eb + 3 < N_EDGES) ? eb + 3 : eb;
        int sa = ei[eb], da = ei[N_EDGES + eb];
        int sb = ei[e1], db = ei[N_EDGES + e1];
        int sc = ei[e2], dc = ei[N_EDGES + e2];
        int sd = ei[e3], dd = ei[N_EDGES + e3];
        float4 ua = ld4h(u + sa * 32 + q * 4);
        float4 va = ld4h(v + da * 32 + q * 4);
        float4 ub = ld4h(u + sb * 32 + q * 4);
        float4 vb = ld4h(v + db * 32 + q * 4);
        float4 uc = ld4h(u + sc * 32 + q * 4);
        float4 vc = ld4h(v + dc * 32 + q * 4);
        float4 ud = ld4h(u + sd * 32 + q * 4);
        float4 vd = ld4h(v + dd * 32 + q * 4);
        float s0 = fmaxf(ua.x + va.x, 0.f) * w2q.x + fmaxf(ua.y + va.y, 0.f) * w2q.y
                 + fmaxf(ua.z + va.z, 0.f) * w2q.z + fmaxf(ua.w + va.w, 0.f) * w2q.w;
        float s1 = fmaxf(ub.x + vb.x, 0.f) * w2q.x + fmaxf(ub.y + vb.y, 0.f) * w2q.y
                 + fmaxf(ub.z + vb.z, 0.f) * w2q.z + fmaxf(ub.w + vb.w, 0.f) * w2q.w;
        float s2 = fmaxf(uc.x + vc.x, 0.f) * w2q.x + fmaxf(uc.y + vc.y, 0.f) * w2q.y
                 + fmaxf(uc.z + vc.z, 0.f) * w2q.z + fmaxf(uc.w + vc.w, 0.f) * w2q.w;
        float s3 = fmaxf(ud.x + vd.x, 0.f) * w2q.x + fmaxf(ud.y + vd.y, 0.f) * w2q.y
                 + fmaxf(ud.z + vd.z, 0.f) * w2q.z + fmaxf(ud.w + vd.w, 0.f) * w2q.w;
        s0 += __shfl_xor(s0, 1, 8); s0 += __shfl_xor(s0, 2, 8); s0 += __shfl_xor(s0, 4, 8);
        s1 += __shfl_xor(s1, 1, 8); s1 += __shfl_xor(s1, 2, 8); s1 += __shfl_xor(s1, 4, 8);
        s2 += __shfl_xor(s2, 1, 8); s2 += __shfl_xor(s2, 2, 8); s2 += __shfl_xor(s2, 4, 8);
        s3 += __shfl_xor(s3, 1, 8); s3 += __shfl_xor(s3, 2, 8); s3 += __shfl_xor(s3, 4, 8);
        if (q == 0) {
            out[eb] = fmaxf(s0 + mb20, 0.f);
            if (eb + 1 < N_EDGES) out[eb + 1] = fmaxf(s1 + mb20, 0.f);
            if (eb + 2 < N_EDGES) out[eb + 2] = fmaxf(s2 + mb20, 0.f);
            if (eb + 3 < N_EDGES) out[eb + 3] = fmaxf(s3 + mb20, 0.f);
        }
    }
}

// ---------------------------------------------------------------- launch
extern "C" void kernel_launch(void* const* d_in, const int* in_sizes, int n_in,
                              void* d_out, int out_size, void* d_ws, size_t ws_size,
                              hipStream_t stream) {
    const float* x    = (const float*)d_in[0];
    const int*   ei   = (const int*)d_in[1];
    const float* w1   = (const float*)d_in[2];
    const float* as1  = (const float*)d_in[3];
    const float* ad1  = (const float*)d_in[4];
    const float* b1   = (const float*)d_in[5];
    const float* w2   = (const float*)d_in[6];
    const float* as2  = (const float*)d_in[7];
    const float* ad2  = (const float*)d_in[8];
    const float* b2   = (const float*)d_in[9];
    const float* mw1  = (const float*)d_in[10];
    const float* mb1  = (const float*)d_in[11];
    const float* mw2  = (const float*)d_in[12];
    const float* mb2  = (const float*)d_in[13];
    float* out = (float*)d_out;

    const int N = N_NODES;
    // byte-offset workspace layout; p1/h2/u/v 64B-aligned (offsets verified)
    char* base   = (char*)d_ws;
    int* deg     = (int*)(base);                      // N*4
    int* rowptr  = (int*)(base + 400000);             // N*4
    int* bstart  = (int*)(base + 800000);             // (NBUCK+1)*4 = 788 B
    int* bh      = (int*)(base + 1200000);            // BLKB*NBUCK*4 = 306,544 B
    int* csr_src = (int*)(base + 1602048);            // E*4
    float* p1    = (float*)(base + 8002048);          // 8N*4   (%64==0)
    float* a1d   = (float*)(base + 11202048);         // 4N*4
    __half* h2   = (__half*)(base + 12802048);        // 32N*2  (%64==0)
    int* binned  = (int*)(base + 19202048);           // E*4 (disjoint lifetime vs h2 region tail)
    float* a2s   = (float*)(base + 25602048);         // N*4
    float* a2d   = (float*)(base + 26002048);         // N*4
    __half* u    = (__half*)(base + 26402048);        // 32N*2  (%64==0)
    __half* v    = (__half*)(base + 32802048);        // 32N*2  (%64==0)
    float* qv    = (float*)(base + 39202048);         // 24

    const int nb = (N + 255) / 256;

    kA_hist<<<BLKB, 256, 0, stream>>>(ei, bh);
    kS1<<<NBUCK, 256, 0, stream>>>(bh, bstart);
    kS2<<<1, 256, 0, stream>>>(bstart);
    kB_bin<<<BLKB, 256, 0, stream>>>(ei, bh, bstart, binned);
    kC_sort<<<NBUCK, 256, 0, stream>>>(bstart, binned, deg, rowptr, csr_src);

    k_q<<<1, 32, 0, stream>>>(w1, as1, ad1, qv);
    k_node1<<<nb, 256, 0, stream>>>(x, qv, a1d, p1);

    k_gat1<<<G1_BLOCKS, 256, 0, stream>>>(rowptr, deg, csr_src, p1, w1, a1d,
                                          b1, w2, as2, ad2, h2, a2s, a2d);

    k_gat2<<<G2_BLOCKS, 256, 0, stream>>>(rowptr, deg, csr_src, h2, a2s, a2d, b2,
                                          mw1, mb1, u, v);

    k_mlp<<<MLP_BLOCKS, 256, 0, stream>>>(ei, u, v, mw2, mb2, out);
}

// Round 10
// 283.043 us; speedup vs baseline: 1.4463x; 1.0051x over previous
//
#include <hip/hip_runtime.h>
#include <hip/hip_fp16.h>
#include <math.h>

#define N_NODES 100000
#define N_EDGES 1600000
#define NEG_SLOPE 0.2f
#define EPS 1e-16f

// bucket sort geometry: 196 buckets of 512 nodes; 391 blocks x 4096 edges
#define NBUCK 196
#define CHUNK 4096
#define BLKB 391

__device__ __forceinline__ float lrelu(float v) { return v > 0.f ? v : NEG_SLOPE * v; }

// load 4 halfs -> float4 (single 8B load)
__device__ __forceinline__ float4 ld4h(const __half* p) {
    uint2 r = *(const uint2*)p;
    __half2 h0 = *reinterpret_cast<const __half2*>(&r.x);
    __half2 h1 = *reinterpret_cast<const __half2*>(&r.y);
    float2 f0 = __half22float2(h0), f1 = __half22float2(h1);
    return make_float4(f0.x, f0.y, f1.x, f1.y);
}

// load 8 halfs -> 8 floats (single 16B load)
__device__ __forceinline__ void ld8h(const __half* p, float* f) {
    uint4 r = *(const uint4*)p;
    __half2 h0 = *reinterpret_cast<const __half2*>(&r.x);
    __half2 h1 = *reinterpret_cast<const __half2*>(&r.y);
    __half2 h2 = *reinterpret_cast<const __half2*>(&r.z);
    __half2 h3 = *reinterpret_cast<const __half2*>(&r.w);
    float2 f0 = __half22float2(h0), f1 = __half22float2(h1);
    float2 f2 = __half22float2(h2), f3 = __half22float2(h3);
    f[0] = f0.x; f[1] = f0.y; f[2] = f1.x; f[3] = f1.y;
    f[4] = f2.x; f[5] = f2.y; f[6] = f3.x; f[7] = f3.y;
}

// ---------------------------------------------------------------- Pass A: per-block coarse histogram (LDS only)
__global__ void kA_hist(const int* __restrict__ ei, int* __restrict__ bh) {
    __shared__ int hist[NBUCK];
    int tid = threadIdx.x, b = blockIdx.x;
    if (tid < NBUCK) hist[tid] = 0;
    __syncthreads();
    int base = b * CHUNK;
    #pragma unroll
    for (int i = 0; i < CHUNK / 256; i++) {
        int e = base + i * 256 + tid;
        if (e < N_EDGES) {
            int dst = ei[N_EDGES + e];
            atomicAdd(&hist[dst >> 9], 1);
        }
    }
    __syncthreads();
    if (tid < NBUCK) bh[b * NBUCK + tid] = hist[tid];
}

// ---------------------------------------------------------------- S1: column scan of bh (one block per bucket)
__global__ void kS1(int* __restrict__ bh, int* __restrict__ bucketStart) {
    __shared__ int tsum[256];
    int k = blockIdx.x, t = threadIdx.x;
    int j0 = 2 * t, j1 = 2 * t + 1;
    int v0 = (j0 < BLKB) ? bh[j0 * NBUCK + k] : 0;
    int v1 = (j1 < BLKB) ? bh[j1 * NBUCK + k] : 0;
    int s = v0 + v1;
    tsum[t] = s;
    __syncthreads();
    for (int off = 1; off < 256; off <<= 1) {
        int tv = (t >= off) ? tsum[t - off] : 0;
        __syncthreads();
        tsum[t] += tv;
        __syncthreads();
    }
    int excl = tsum[t] - s;
    if (j0 < BLKB) bh[j0 * NBUCK + k] = excl;
    if (j1 < BLKB) bh[j1 * NBUCK + k] = excl + v0;
    if (t == 255) bucketStart[k] = tsum[255];   // column total (scanned by S2)
}

// ---------------------------------------------------------------- S2: scan bucket totals -> bucket starts (+ total at [NBUCK])
__global__ void kS2(int* __restrict__ bucketStart) {
    __shared__ int tmp[256];
    int t = threadIdx.x;
    int v = (t < NBUCK) ? bucketStart[t] : 0;
    tmp[t] = v;
    __syncthreads();
    for (int off = 1; off < 256; off <<= 1) {
        int tv = (t >= off) ? tmp[t - off] : 0;
        __syncthreads();
        tmp[t] += tv;
        __syncthreads();
    }
    if (t < NBUCK) bucketStart[t] = tmp[t] - v;
    if (t == NBUCK - 1) bucketStart[NBUCK] = tmp[t];
}

// ---------------------------------------------------------------- Pass B: bin edges by coarse bucket (LDS cursors, coalesced-run writes)
__global__ void kB_bin(const int* __restrict__ ei, const int* __restrict__ bh,
                       const int* __restrict__ bucketStart, int* __restrict__ binned) {
    __shared__ int cur[NBUCK];
    int tid = threadIdx.x, b = blockIdx.x;
    if (tid < NBUCK) cur[tid] = bucketStart[tid] + bh[b * NBUCK + tid];
    __syncthreads();
    int base = b * CHUNK;
    #pragma unroll
    for (int i = 0; i < CHUNK / 256; i++) {
        int e = base + i * 256 + tid;
        if (e < N_EDGES) {
            int src = ei[e], dst = ei[N_EDGES + e];
            int pos = atomicAdd(&cur[dst >> 9], 1);
            binned[pos] = src | ((dst & 511) << 17);
        }
    }
}

// ---------------------------------------------------------------- Pass C: per-bucket counting sort -> deg, rowptr, csr_src
__global__ void kC_sort(const int* __restrict__ bucketStart, const int* __restrict__ binned,
                        int* __restrict__ deg, int* __restrict__ rowptr,
                        int* __restrict__ csr_src) {
    __shared__ int cnt[512];
    __shared__ int pfx[512];
    __shared__ int bsum[256];
    int t = threadIdx.x, k = blockIdx.x;
    int s0 = bucketStart[k], s1 = bucketStart[k + 1];
    cnt[t] = 0; cnt[t + 256] = 0;
    __syncthreads();
    for (int i = s0 + t; i < s1; i += 256)
        atomicAdd(&cnt[binned[i] >> 17], 1);
    __syncthreads();
    int a0 = cnt[2 * t], a1 = cnt[2 * t + 1];
    int s = a0 + a1;
    bsum[t] = s;
    __syncthreads();
    for (int off = 1; off < 256; off <<= 1) {
        int tv = (t >= off) ? bsum[t - off] : 0;
        __syncthreads();
        bsum[t] += tv;
        __syncthreads();
    }
    int excl = bsum[t] - s;
    pfx[2 * t] = excl;
    pfx[2 * t + 1] = excl + a0;
    int nb0 = k << 9;
    int n0 = nb0 + 2 * t, n1 = nb0 + 2 * t + 1;
    if (n0 < N_NODES) { deg[n0] = a0; rowptr[n0] = s0 + excl; }
    if (n1 < N_NODES) { deg[n1] = a1; rowptr[n1] = s0 + excl + a0; }
    __syncthreads();
    for (int i = s0 + t; i < s1; i += 256) {
        int pkd = binned[i];
        int pos = s0 + atomicAdd(&pfx[pkd >> 17], 1);
        csr_src[pos] = pkd & 0x1FFFF;
    }
}

// ---------------------------------------------------------------- K-Q: qs[h] = W1_h^T a_src_h, qd[h] = W1_h^T a_dst_h  (24 floats)
__global__ void k_q(const float* __restrict__ w1, const float* __restrict__ as1,
                    const float* __restrict__ ad1, float* __restrict__ qv) {
    int t = threadIdx.x;
    if (t >= 24) return;
    int c = t % 3, h = (t / 3) % 4, side = t / 12;
    const float* att = side ? ad1 : as1;
    float acc = 0.f;
    for (int cc = 0; cc < 32; cc++)
        acc += att[h * 32 + cc] * w1[(h * 32 + cc) * 3 + c];
    qv[t] = acc;
}

// ---------------------------------------------------------------- K-NODE1: a1d = x.qd ; p1[n] = {a1s[4], x0,x1,x2,1} (32B row)
__global__ void k_node1(const float* __restrict__ x, const float* __restrict__ qv,
                        float* __restrict__ a1d, float* __restrict__ p1) {
    int n = blockIdx.x * blockDim.x + threadIdx.x;
    if (n >= N_NODES) return;
    float x0 = x[n * 3], x1 = x[n * 3 + 1], x2 = x[n * 3 + 2];
    float4 s, d;
    s.x = x0 * qv[0]  + x1 * qv[1]  + x2 * qv[2];
    s.y = x0 * qv[3]  + x1 * qv[4]  + x2 * qv[5];
    s.z = x0 * qv[6]  + x1 * qv[7]  + x2 * qv[8];
    s.w = x0 * qv[9]  + x1 * qv[10] + x2 * qv[11];
    d.x = x0 * qv[12] + x1 * qv[13] + x2 * qv[14];
    d.y = x0 * qv[15] + x1 * qv[16] + x2 * qv[17];
    d.z = x0 * qv[18] + x1 * qv[19] + x2 * qv[20];
    d.w = x0 * qv[21] + x1 * qv[22] + x2 * qv[23];
    ((float4*)a1d)[n] = d;
    ((float4*)p1)[n * 2]     = s;
    float4 xx; xx.x = x0; xx.y = x1; xx.z = x2; xx.w = 1.f;
    ((float4*)p1)[n * 2 + 1] = xx;
}

// ---------------------------------------------------------------- K-GAT1 v3b: 32 nodes/block, 8 lanes/node (2x wave count)
// Rewrite of v3 (rounds 8/9 hit container-level failures; audit found no
// fault — this is the same algorithm re-expressed). 8 lanes/node in phase A
// (stride-8 edge partition, butterfly xor 1,2,4), 8 nodes/wave in phase B.
// 3125 blocks = 12500 waves = 12.2/SIMD available (was 6.1).
#define G1_BLOCKS ((N_NODES + 31) / 32)
__global__ void k_gat1(const int* __restrict__ rowptr, const int* __restrict__ deg,
                       const int* __restrict__ csr_src,
                       const float* __restrict__ p1, const float* __restrict__ w1,
                       const float* __restrict__ a1d,
                       const float* __restrict__ b1, const float* __restrict__ w2,
                       const float* __restrict__ as2, const float* __restrict__ ad2,
                       __half* __restrict__ h2, float* __restrict__ a2s, float* __restrict__ a2d) {
    __shared__ float sm[32][16];      // per-node: 4 heads x {s0,s1,s2,den}
    __shared__ float f1s[4][128];
    int tid = threadIdx.x;
    int wave = tid >> 6, lane = tid & 63;
    int o = lane & 31, half = lane >> 5;
    int k0 = half * 64;

    // ---- phase A: node = block*32 + wave*8 + (lane>>3); ep = lane&7 = edge phase
    int nl = wave * 8 + (lane >> 3);
    int ep = lane & 7;
    int n  = blockIdx.x * 32 + nl;
    if (n < N_NODES) {
        float4 ad4 = ((const float4*)a1d)[n];          // broadcast across the octet
        float adv0 = ad4.x, adv1 = ad4.y, adv2 = ad4.z, adv3 = ad4.w;
        int beg = rowptr[n], cnt = deg[n];
        float s0h[4] = {0.f, 0.f, 0.f, 0.f};
        float s1h[4] = {0.f, 0.f, 0.f, 0.f};
        float s2h[4] = {0.f, 0.f, 0.f, 0.f};
        float dnh[4] = {0.f, 0.f, 0.f, 0.f};
        int t = ep;
        int lim = cnt - 8;                              // pair iteration valid while t < lim
        for (; t < lim; t += 16) {                      // edges t and t+8: 4 gathers in flight
            int i0 = csr_src[beg + t], i1 = csr_src[beg + t + 8];
            float4 A0 = ((const float4*)p1)[i0 * 2], X0 = ((const float4*)p1)[i0 * 2 + 1];
            float4 A1 = ((const float4*)p1)[i1 * 2], X1 = ((const float4*)p1)[i1 * 2 + 1];
            float av0[4] = {A0.x, A0.y, A0.z, A0.w};
            float av1[4] = {A1.x, A1.y, A1.z, A1.w};
            float ad_[4] = {adv0, adv1, adv2, adv3};
            #pragma unroll
            for (int hh = 0; hh < 4; hh++) {
                float e0 = __expf(lrelu(av0[hh] + ad_[hh]));
                float e1 = __expf(lrelu(av1[hh] + ad_[hh]));
                s0h[hh] += e0 * X0.x + e1 * X1.x;
                s1h[hh] += e0 * X0.y + e1 * X1.y;
                s2h[hh] += e0 * X0.z + e1 * X1.z;
                dnh[hh] += e0 + e1;
            }
        }
        for (; t < cnt; t += 8) {                       // remainder: at most one edge
            int i0 = csr_src[beg + t];
            float4 A0 = ((const float4*)p1)[i0 * 2], X0 = ((const float4*)p1)[i0 * 2 + 1];
            float av0[4] = {A0.x, A0.y, A0.z, A0.w};
            float ad_[4] = {adv0, adv1, adv2, adv3};
            #pragma unroll
            for (int hh = 0; hh < 4; hh++) {
                float e0 = __expf(lrelu(av0[hh] + ad_[hh]));
                s0h[hh] += e0 * X0.x;
                s1h[hh] += e0 * X0.y;
                s2h[hh] += e0 * X0.z;
                dnh[hh] += e0;
            }
        }
        // 8-lane butterfly (octet is exec-uniform: same n) — all lanes get full sums
        #pragma unroll
        for (int hh = 0; hh < 4; hh++) {
            s0h[hh] += __shfl_xor(s0h[hh], 1); s0h[hh] += __shfl_xor(s0h[hh], 2); s0h[hh] += __shfl_xor(s0h[hh], 4);
            s1h[hh] += __shfl_xor(s1h[hh], 1); s1h[hh] += __shfl_xor(s1h[hh], 2); s1h[hh] += __shfl_xor(s1h[hh], 4);
            s2h[hh] += __shfl_xor(s2h[hh], 1); s2h[hh] += __shfl_xor(s2h[hh], 2); s2h[hh] += __shfl_xor(s2h[hh], 4);
            dnh[hh] += __shfl_xor(dnh[hh], 1); dnh[hh] += __shfl_xor(dnh[hh], 2); dnh[hh] += __shfl_xor(dnh[hh], 4);
        }
        if (ep < 4) {   // lanes 0..3 write heads 0..3 (static-index select)
            float4 r;
            r.x = ep == 0 ? s0h[0] : ep == 1 ? s0h[1] : ep == 2 ? s0h[2] : s0h[3];
            r.y = ep == 0 ? s1h[0] : ep == 1 ? s1h[1] : ep == 2 ? s1h[2] : s1h[3];
            r.z = ep == 0 ? s2h[0] : ep == 1 ? s2h[1] : ep == 2 ? s2h[2] : s2h[3];
            r.w = ep == 0 ? dnh[0] : ep == 1 ? dnh[1] : ep == 2 ? dnh[2] : dnh[3];
            *(float4*)&sm[nl][ep * 4] = r;
        }
    }
    // same-wave LDS write->read below: no barrier needed

    // per-lane w2 column loaded AFTER phase A (keeps gather-loop VGPR pressure low)
    float w2r[64];
    {
        const float4* wp = (const float4*)(w2 + o * 128 + k0);
        #pragma unroll
        for (int q = 0; q < 16; q++) {
            float4 t4 = wp[q];
            w2r[q * 4 + 0] = t4.x; w2r[q * 4 + 1] = t4.y;
            w2r[q * 4 + 2] = t4.z; w2r[q * 4 + 3] = t4.w;
        }
    }

    // ---- phase B: wave processes its own 8 nodes
    int j = lane, j2 = lane + 64;
    int h0 = j >> 5;
    float wa0 = w1[j * 3], wa1 = w1[j * 3 + 1], wa2 = w1[j * 3 + 2];
    float wb0 = w1[j2 * 3], wb1 = w1[j2 * 3 + 1], wb2 = w1[j2 * 3 + 2];
    float b1j = b1[j], b1j2 = b1[j2];
    float as2o = as2[o], ad2o = ad2[o];
    const float* f = f1s[wave];

    #pragma unroll 1
    for (int i = 0; i < 8; i++) {
        int n2 = blockIdx.x * 32 + wave * 8 + i;
        if (n2 >= N_NODES) break;
        const float* S = sm[wave * 8 + i];
        float v0 = (wa0 * S[h0 * 4] + wa1 * S[h0 * 4 + 1] + wa2 * S[h0 * 4 + 2])
                   / (S[h0 * 4 + 3] + EPS) + b1j;
        float v1 = (wb0 * S[(2 + h0) * 4] + wb1 * S[(2 + h0) * 4 + 1] + wb2 * S[(2 + h0) * 4 + 2])
                   / (S[(2 + h0) * 4 + 3] + EPS) + b1j2;
        f1s[wave][j]  = v0 > 0.f ? v0 : expm1f(v0);
        f1s[wave][j2] = v1 > 0.f ? v1 : expm1f(v1);
        float acc = 0.f;
        #pragma unroll
        for (int t = 0; t < 64; t++)
            acc += f[k0 + t] * w2r[t];
        acc += __shfl_down(acc, 32);
        if (half == 0) {
            h2[n2 * 32 + o] = __float2half(acc);   // fp16 row (64 B, coalesced)
            float ps = acc * as2o, pd = acc * ad2o;
            #pragma unroll
            for (int off = 16; off; off >>= 1) {
                ps += __shfl_xor(ps, off);
                pd += __shfl_xor(pd, off);
            }
            if (o == 0) { a2s[n2] = ps; a2d[n2] = pd; }
        }
    }
}

// ---------------------------------------------------------------- K-GAT2 v5: 16 lanes/node, 4 nodes/wave (4x miss chains)
#define G2_BLOCKS ((N_NODES + 15) / 16)
__global__ void k_gat2(const int* __restrict__ rowptr, const int* __restrict__ deg,
                       const int* __restrict__ csr_src,
                       const __half* __restrict__ h2, const float* __restrict__ a2s,
                       const float* __restrict__ a2d, const float* __restrict__ b2,
                       const float* __restrict__ mw1, const float* __restrict__ mb1,
                       __half* __restrict__ u, __half* __restrict__ v) {
    __shared__ float Ws2[2][32 * 36];    // [half][c*36+k]; row start 144B (16B-aligned)
    __shared__ int2  pk[4][64];          // per-wave staged (idx, e-bits), 16 slots/group
    __shared__ float4 hfs[4][4][8];      // [wave][group][8 quads] = hf vector (32 floats)
    int tid = threadIdx.x;
    for (int i = tid; i < 2048; i += 256) {
        int c = i >> 6, col = i & 63;
        Ws2[col >> 5][c * 36 + (col & 31)] = mw1[i];
    }
    __syncthreads();
    int lane = tid & 63, w = tid >> 6;
    int nl = lane >> 4, sl = lane & 15;          // group (node) / sub-lane
    int eg2 = sl >> 2, qq = sl & 3;              // edge slot / 16-B chunk
    int n = blockIdx.x * 16 + w * 4 + nl;        // one node per group, no stride loop
    float4 b2a = ((const float4*)b2)[qq * 2];    // channels qq*8 .. qq*8+3
    float4 b2b = ((const float4*)b2)[qq * 2 + 1];// channels qq*8+4 .. qq*8+7

    int beg = 0, cnt = 0;
    float ad = 0.f;
    if (n < N_NODES) { beg = rowptr[n]; cnt = deg[n]; ad = a2d[n]; }

    float acc[8] = {0.f, 0.f, 0.f, 0.f, 0.f, 0.f, 0.f, 0.f};
    float den = 0.f;
    int pkbase = (nl << 4);
    for (int b16 = 0; b16 < cnt; b16 += 16) {    // group-divergent, exec-masked
        int li = b16 + sl;
        int idx = (li < cnt) ? csr_src[beg + li] : 0;
        float e = 0.f;
        if (li < cnt) e = __expf(lrelu(a2s[idx] + ad));
        den += e;
        pk[w][pkbase + sl] = make_int2(idx, __float_as_int(e)); // same-wave stage
        #pragma unroll
        for (int p = 0; p < 4; p++) {            // fixed 4 steps: 4 rows in flight/group
            int2 pe = pk[w][pkbase + p * 4 + eg2];
            float g[8];
            ld8h(h2 + pe.x * 32 + qq * 8, g);    // 16-B gather (8 halfs)
            float ee = __int_as_float(pe.y);     // 0 for pads
            acc[0] += ee * g[0]; acc[1] += ee * g[1];
            acc[2] += ee * g[2]; acc[3] += ee * g[3];
            acc[4] += ee * g[4]; acc[5] += ee * g[5];
            acc[6] += ee * g[6]; acc[7] += ee * g[7];
        }
    }
    // reduce across the 4 edge slots (within 16-lane group)
    #pragma unroll
    for (int j = 0; j < 8; j++) {
        float vv = acc[j];
        vv += __shfl_xor(vv, 4);
        vv += __shfl_xor(vv, 8);
        acc[j] = vv;
    }
    den += __shfl_xor(den, 1); den += __shfl_xor(den, 2);
    den += __shfl_xor(den, 4); den += __shfl_xor(den, 8);
    float inv = 1.f / (den + EPS);
    if (sl < 4) {                                // sl<4 => eg2=0, qq=sl
        float4 ha, hb;
        ha.x = acc[0] * inv + b2a.x; ha.y = acc[1] * inv + b2a.y;
        ha.z = acc[2] * inv + b2a.z; ha.w = acc[3] * inv + b2a.w;
        hb.x = acc[4] * inv + b2b.x; hb.y = acc[5] * inv + b2b.y;
        hb.z = acc[6] * inv + b2b.z; hb.w = acc[7] * inv + b2b.w;
        hfs[w][nl][qq * 2]     = ha;             // same-wave stage
        hfs[w][nl][qq * 2 + 1] = hb;
    }
    // epilogue: 16 lanes per node, 4 output channels per lane
    if (n < N_NODES) {
        int half_o = sl >> 3, c4 = (sl & 7) * 4;
        __half* outp = half_o ? v : u;
        float r0 = half_o ? 0.f : mb1[c4 + 0];
        float r1 = half_o ? 0.f : mb1[c4 + 1];
        float r2 = half_o ? 0.f : mb1[c4 + 2];
        float r3 = half_o ? 0.f : mb1[c4 + 3];
        const float* Wb = &Ws2[half_o][0];
        #pragma unroll
        for (int q = 0; q < 8; q++) {
            float4 hq = hfs[w][nl][q];           // broadcast within group
            float4 W0 = *(const float4*)&Wb[(c4 + 0) * 36 + q * 4];
            float4 W1 = *(const float4*)&Wb[(c4 + 1) * 36 + q * 4];
            float4 W2 = *(const float4*)&Wb[(c4 + 2) * 36 + q * 4];
            float4 W3 = *(const float4*)&Wb[(c4 + 3) * 36 + q * 4];
            r0 += W0.x * hq.x + W0.y * hq.y + W0.z * hq.z + W0.w * hq.w;
            r1 += W1.x * hq.x + W1.y * hq.y + W1.z * hq.z + W1.w * hq.w;
            r2 += W2.x * hq.x + W2.y * hq.y + W2.z * hq.z + W2.w * hq.w;
            r3 += W3.x * hq.x + W3.y * hq.y + W3.z * hq.z + W3.w * hq.w;
        }
        __half2 p0, p1;
        p0.x = __float2half(r0); p0.y = __float2half(r1);
        p1.x = __float2half(r2); p1.y = __float2half(r3);
        uint2 st;
        st.x = *reinterpret_cast<unsigned int*>(&p0);
        st.y = *reinterpret_cast<unsigned int*>(&p1);
        *reinterpret_cast<uint2*>(outp + n * 32 + c4) = st;  // 8-B aligned store
    }
}

// ---------------------------------------------------------------- K-MLP: 8 lanes/edge, 4 edges/iter, fp16 u/v rows (1 line each)
#define MLP_BLOCKS 4096
__global__ void k_mlp(const int* __restrict__ ei, const __half* __restrict__ u,
                      const __half* __restrict__ v, const float* __restrict__ mw2,
                      const float* __restrict__ mb2, float* __restrict__ out) {
    int tid = threadIdx.x;
    int q = tid & 7;
    float4 w2q = ((const float4*)mw2)[q];
    float mb20 = mb2[0];
    int g = blockIdx.x * 32 + (tid >> 3);
    const int stride = MLP_BLOCKS * 32 * 4;
    for (int e = g * 4; e < N_EDGES; e += stride) {
        int eb = e;
        int e1 = (eb + 1 < N_EDGES) ? eb + 1 : eb;
        int e2 = (eb + 2 < N_EDGES) ? eb + 2 : eb;
        int e3 = (eb + 3 < N_EDGES) ? eb + 3 : eb;
        int sa = ei[eb], da = ei[N_EDGES + eb];
        int sb = ei[e1], db = ei[N_EDGES + e1];
        int sc = ei[e2], dc = ei[N_EDGES + e2];
        int sd = ei[e3], dd = ei[N_EDGES + e3];
        float4 ua = ld4h(u + sa * 32 + q * 4);
        float4 va = ld4h(v + da * 32 + q * 4);
        float4 ub = ld4h(u + sb * 32 + q * 4);
        float4 vb = ld4h(v + db * 32 + q * 4);
        float4 uc = ld4h(u + sc * 32 + q * 4);
        float4 vc = ld4h(v + dc * 32 + q * 4);
        float4 ud = ld4h(u + sd * 32 + q * 4);
        float4 vd = ld4h(v + dd * 32 + q * 4);
        float s0 = fmaxf(ua.x + va.x, 0.f) * w2q.x + fmaxf(ua.y + va.y, 0.f) * w2q.y
                 + fmaxf(ua.z + va.z, 0.f) * w2q.z + fmaxf(ua.w + va.w, 0.f) * w2q.w;
        float s1 = fmaxf(ub.x + vb.x, 0.f) * w2q.x + fmaxf(ub.y + vb.y, 0.f) * w2q.y
                 + fmaxf(ub.z + vb.z, 0.f) * w2q.z + fmaxf(ub.w + vb.w, 0.f) * w2q.w;
        float s2 = fmaxf(uc.x + vc.x, 0.f) * w2q.x + fmaxf(uc.y + vc.y, 0.f) * w2q.y
                 + fmaxf(uc.z + vc.z, 0.f) * w2q.z + fmaxf(uc.w + vc.w, 0.f) * w2q.w;
        float s3 = fmaxf(ud.x + vd.x, 0.f) * w2q.x + fmaxf(ud.y + vd.y, 0.f) * w2q.y
                 + fmaxf(ud.z + vd.z, 0.f) * w2q.z + fmaxf(ud.w + vd.w, 0.f) * w2q.w;
        s0 += __shfl_xor(s0, 1, 8); s0 += __shfl_xor(s0, 2, 8); s0 += __shfl_xor(s0, 4, 8);
        s1 += __shfl_xor(s1, 1, 8); s1 += __shfl_xor(s1, 2, 8); s1 += __shfl_xor(s1, 4, 8);
        s2 += __shfl_xor(s2, 1, 8); s2 += __shfl_xor(s2, 2, 8); s2 += __shfl_xor(s2, 4, 8);
        s3 += __shfl_xor(s3, 1, 8); s3 += __shfl_xor(s3, 2, 8); s3 += __shfl_xor(s3, 4, 8);
        if (q == 0) {
            out[eb] = fmaxf(s0 + mb20, 0.f);
            if (eb + 1 < N_EDGES) out[eb + 1] = fmaxf(s1 + mb20, 0.f);
            if (eb + 2 < N_EDGES) out[eb + 2] = fmaxf(s2 + mb20, 0.f);
            if (eb + 3 < N_EDGES) out[eb + 3] = fmaxf(s3 + mb20, 0.f);
        }
    }
}

// ---------------------------------------------------------------- launch
extern "C" void kernel_launch(void* const* d_in, const int* in_sizes, int n_in,
                              void* d_out, int out_size, void* d_ws, size_t ws_size,
                              hipStream_t stream) {
    const float* x    = (const float*)d_in[0];
    const int*   ei   = (const int*)d_in[1];
    const float* w1   = (const float*)d_in[2];
    const float* as1  = (const float*)d_in[3];
    const float* ad1  = (const float*)d_in[4];
    const float* b1   = (const float*)d_in[5];
    const float* w2   = (const float*)d_in[6];
    const float* as2  = (const float*)d_in[7];
    const float* ad2  = (const float*)d_in[8];
    const float* b2   = (const float*)d_in[9];
    const float* mw1  = (const float*)d_in[10];
    const float* mb1  = (const float*)d_in[11];
    const float* mw2  = (const float*)d_in[12];
    const float* mb2  = (const float*)d_in[13];
    float* out = (float*)d_out;

    const int N = N_NODES;
    // byte-offset workspace layout; p1/h2/u/v 64B-aligned (offsets verified)
    char* base   = (char*)d_ws;
    int* deg     = (int*)(base);                      // N*4
    int* rowptr  = (int*)(base + 400000);             // N*4
    int* bstart  = (int*)(base + 800000);             // (NBUCK+1)*4 = 788 B
    int* bh      = (int*)(base + 1200000);            // BLKB*NBUCK*4 = 306,544 B
    int* csr_src = (int*)(base + 1602048);            // E*4
    float* p1    = (float*)(base + 8002048);          // 8N*4   (%64==0)
    float* a1d   = (float*)(base + 11202048);         // 4N*4
    __half* h2   = (__half*)(base + 12802048);        // 32N*2  (%64==0)
    int* binned  = (int*)(base + 19202048);           // E*4 (disjoint lifetime vs h2 region tail)
    float* a2s   = (float*)(base + 25602048);         // N*4
    float* a2d   = (float*)(base + 26002048);         // N*4
    __half* u    = (__half*)(base + 26402048);        // 32N*2  (%64==0)
    __half* v    = (__half*)(base + 32802048);        // 32N*2  (%64==0)
    float* qv    = (float*)(base + 39202048);         // 24

    const int nb = (N + 255) / 256;

    kA_hist<<<BLKB, 256, 0, stream>>>(ei, bh);
    kS1<<<NBUCK, 256, 0, stream>>>(bh, bstart);
    kS2<<<1, 256, 0, stream>>>(bstart);
    kB_bin<<<BLKB, 256, 0, stream>>>(ei, bh, bstart, binned);
    kC_sort<<<NBUCK, 256, 0, stream>>>(bstart, binned, deg, rowptr, csr_src);

    k_q<<<1, 32, 0, stream>>>(w1, as1, ad1, qv);
    k_node1<<<nb, 256, 0, stream>>>(x, qv, a1d, p1);

    k_gat1<<<G1_BLOCKS, 256, 0, stream>>>(rowptr, deg, csr_src, p1, w1, a1d,
                                          b1, w2, as2, ad2, h2, a2s, a2d);

    k_gat2<<<G2_BLOCKS, 256, 0, stream>>>(rowptr, deg, csr_src, h2, a2s, a2d, b2,
                                          mw1, mb1, u, v);

    k_mlp<<<MLP_BLOCKS, 256, 0, stream>>>(ei, u, v, mw2, mb2, out);
}